// Round 4
// baseline (662.118 us; speedup 1.0000x reference)
//
#include <hip/hip_runtime.h>
#include <math.h>

#define N_NODES 50000
#define D 128       // d_in == d_hid
#define D_OUT 64

// ---------------------------------------------------------------------------
// CSR build step 1: in-degree histogram
// ---------------------------------------------------------------------------
__global__ __launch_bounds__(256) void hist_kernel(
    const int* __restrict__ dst, int* __restrict__ deg, int E)
{
    int e = blockIdx.x * blockDim.x + threadIdx.x;
    if (e < E) atomicAdd(&deg[dst[e]], 1);
}

// ---------------------------------------------------------------------------
// CSR build step 2: exclusive scan of deg -> row_ptr (single block)
// ---------------------------------------------------------------------------
__global__ __launch_bounds__(256) void scan_kernel(
    const int* __restrict__ deg, int* __restrict__ row_ptr, int n)
{
    __shared__ int sums[256];
    __shared__ int excl[256];
    const int t = threadIdx.x;
    const int chunk = (n + 255) / 256;
    const int start = t * chunk;
    const int end   = min(start + chunk, n);

    int s = 0;
    for (int i = start; i < end; ++i) s += deg[i];
    sums[t] = s;
    __syncthreads();

    if (t == 0) {
        int run = 0;
        for (int i = 0; i < 256; ++i) { excl[i] = run; run += sums[i]; }
        row_ptr[n] = run;
    }
    __syncthreads();

    int run = excl[t];
    for (int i = start; i < end; ++i) { row_ptr[i] = run; run += deg[i]; }
}

// ---------------------------------------------------------------------------
// CSR build step 3: bucket-fill edge sources (order within bucket arbitrary)
// ---------------------------------------------------------------------------
__global__ __launch_bounds__(256) void fill_kernel(
    const int* __restrict__ src, const int* __restrict__ dst,
    const int* __restrict__ row_ptr, int* __restrict__ cursor,
    int* __restrict__ esrc, int E)
{
    int e = blockIdx.x * blockDim.x + threadIdx.x;
    if (e >= E) return;
    int d = dst[e];
    int pos = atomicAdd(&cursor[d], 1);
    esrc[row_ptr[d] + pos] = src[e];
}

// ---------------------------------------------------------------------------
// Gather-aggregate: one 64-lane wave per node, float2 per lane (128 floats).
// Writes the premeaned row: agg[i] = sum_{j->i} x[j] / max(deg,1).
// ---------------------------------------------------------------------------
__global__ __launch_bounds__(256) void gather_agg_kernel(
    const float* __restrict__ x,
    const int* __restrict__ row_ptr,
    const int* __restrict__ esrc,
    float* __restrict__ agg,
    int n_nodes)
{
    int gtid = blockIdx.x * blockDim.x + threadIdx.x;
    int node = gtid >> 6;
    int lane = gtid & 63;
    if (node >= n_nodes) return;

    int beg = row_ptr[node];
    int end = row_ptr[node + 1];

    float ax = 0.f, ay = 0.f;
    int p = beg;
    for (; p + 1 < end; p += 2) {
        int s0 = esrc[p];
        int s1 = esrc[p + 1];
        const float2 v0 = *reinterpret_cast<const float2*>(x + (size_t)s0 * D + lane * 2);
        const float2 v1 = *reinterpret_cast<const float2*>(x + (size_t)s1 * D + lane * 2);
        ax += v0.x + v1.x;
        ay += v0.y + v1.y;
    }
    if (p < end) {
        int s0 = esrc[p];
        const float2 v0 = *reinterpret_cast<const float2*>(x + (size_t)s0 * D + lane * 2);
        ax += v0.x;
        ay += v0.y;
    }

    float inv = (end > beg) ? 1.0f / (float)(end - beg) : 0.0f;
    *reinterpret_cast<float2*>(agg + (size_t)node * D + lane * 2) =
        make_float2(ax * inv, ay * inv);
}

// ---------------------------------------------------------------------------
// Fused layer GEMM, no LDS: z[i][j] = A1[i]·Wl[j] + b[j] + A2[i]·Wr[j]
// Block = 256 threads = 16 g-cols x 16 ty-rows; thread computes 4 nodes x TN js,
// js strided (j = g + 16*r) so global stores stay coalesced.
// Signature order (Wl, b, Wr) matches all call sites.
// SOFTMAX=false: relu -> out[node*128+j]; true: log_softmax over BN=TN*16 js.
// ---------------------------------------------------------------------------
template<int TN, bool SOFTMAX>
__global__ __launch_bounds__(256) void layer_kernel(
    const float* __restrict__ A1,    // premeaned agg  [n][128]
    const float* __restrict__ A2,    // x or h1        [n][128]
    const float* __restrict__ Wl,    // [BN][128]
    const float* __restrict__ bias,  // [BN]
    const float* __restrict__ Wr,    // [BN][128]
    float* __restrict__ out,         // [n][BN]
    int n_nodes)
{
    constexpr int BN = TN * 16;
    const int g  = threadIdx.x & 15;
    const int ty = threadIdx.x >> 4;
    const int n0 = blockIdx.x * 64 + ty * 4;

    int nn[4];
#pragma unroll
    for (int i = 0; i < 4; ++i) nn[i] = min(n0 + i, n_nodes - 1);

    float acc[4][TN];
#pragma unroll
    for (int i = 0; i < 4; ++i)
#pragma unroll
        for (int r = 0; r < TN; ++r) acc[i][r] = 0.f;

#pragma unroll
    for (int half = 0; half < 2; ++half) {
        const float* __restrict__ A = half ? A2 : A1;
        const float* __restrict__ W = half ? Wr : Wl;

#pragma unroll 2
        for (int kk = 0; kk < D; kk += 4) {
            float4 a[4];
#pragma unroll
            for (int i = 0; i < 4; ++i)
                a[i] = *reinterpret_cast<const float4*>(A + (size_t)nn[i] * D + kk);
            float4 w[TN];
#pragma unroll
            for (int r = 0; r < TN; ++r)
                w[r] = *reinterpret_cast<const float4*>(W + (size_t)(g + 16 * r) * D + kk);
#pragma unroll
            for (int i = 0; i < 4; ++i)
#pragma unroll
                for (int r = 0; r < TN; ++r) {
                    acc[i][r] = fmaf(a[i].x, w[r].x, acc[i][r]);
                    acc[i][r] = fmaf(a[i].y, w[r].y, acc[i][r]);
                    acc[i][r] = fmaf(a[i].z, w[r].z, acc[i][r]);
                    acc[i][r] = fmaf(a[i].w, w[r].w, acc[i][r]);
                }
        }
    }

    float bj[TN];
#pragma unroll
    for (int r = 0; r < TN; ++r) bj[r] = bias[g + 16 * r];

    if (!SOFTMAX) {
#pragma unroll
        for (int i = 0; i < 4; ++i) {
            int node = n0 + i;
            if (node < n_nodes) {
#pragma unroll
                for (int r = 0; r < TN; ++r) {
                    float v = acc[i][r] + bj[r];
                    out[(size_t)node * BN + g + 16 * r] = fmaxf(v, 0.0f);
                }
            }
        }
    } else {
#pragma unroll
        for (int i = 0; i < 4; ++i) {
            float z[TN];
            float m = -1e30f;
#pragma unroll
            for (int r = 0; r < TN; ++r) {
                z[r] = acc[i][r] + bj[r];
                m = fmaxf(m, z[r]);
            }
            // row = 16 g-lanes (same ty): offsets 1,2,4,8 stay in the group
#pragma unroll
            for (int off = 1; off < 16; off <<= 1)
                m = fmaxf(m, __shfl_xor(m, off));
            float s = 0.f;
#pragma unroll
            for (int r = 0; r < TN; ++r) s += expf(z[r] - m);
#pragma unroll
            for (int off = 1; off < 16; off <<= 1)
                s += __shfl_xor(s, off);
            float lse = m + logf(s);
            int node = n0 + i;
            if (node < n_nodes) {
#pragma unroll
                for (int r = 0; r < TN; ++r)
                    out[(size_t)node * BN + g + 16 * r] = z[r] - lse;
            }
        }
    }
}

// ---------------------------------------------------------------------------
extern "C" void kernel_launch(void* const* d_in, const int* in_sizes, int n_in,
                              void* d_out, int out_size, void* d_ws, size_t ws_size,
                              hipStream_t stream)
{
    const float* x   = (const float*)d_in[0];
    const int*   ei  = (const int*)d_in[1];
    const float* W1l = (const float*)d_in[2];
    const float* b1  = (const float*)d_in[3];
    const float* W1r = (const float*)d_in[4];
    const float* W2l = (const float*)d_in[5];
    const float* b2  = (const float*)d_in[6];
    const float* W2r = (const float*)d_in[7];
    float* out = (float*)d_out;

    const int E = in_sizes[1] / 2;
    const int* src = ei;
    const int* dst = ei + E;

    // workspace layout (floats/ints, all 4B)
    float* agg     = (float*)d_ws;                       // N*D
    float* h1      = agg + (size_t)N_NODES * D;          // N*D
    int*   deg     = (int*)(h1 + (size_t)N_NODES * D);   // N
    int*   row_ptr = deg + N_NODES;                      // N+1
    int*   cursor  = row_ptr + N_NODES + 1;              // N
    int*   esrc    = cursor + N_NODES;                   // E

    const int EB = (E + 255) / 256;

    // ---- CSR build (once; shared by both layers) ----
    hipMemsetAsync(deg,    0, (size_t)N_NODES * sizeof(int), stream);
    hipMemsetAsync(cursor, 0, (size_t)N_NODES * sizeof(int), stream);
    hist_kernel<<<EB, 256, 0, stream>>>(dst, deg, E);
    scan_kernel<<<1, 256, 0, stream>>>(deg, row_ptr, N_NODES);
    fill_kernel<<<EB, 256, 0, stream>>>(src, dst, row_ptr, cursor, esrc, E);

    const int GB = (N_NODES * 64 + 255) / 256;   // gather: 1 wave per node
    const int LB = (N_NODES + 63) / 64;          // layer: 64 nodes per block

    // ---- layer 1 ----
    gather_agg_kernel<<<GB, 256, 0, stream>>>(x, row_ptr, esrc, agg, N_NODES);
    layer_kernel<8, false><<<LB, 256, 0, stream>>>(agg, x, W1l, b1, W1r, h1, N_NODES);

    // ---- layer 2 ----
    gather_agg_kernel<<<GB, 256, 0, stream>>>(h1, row_ptr, esrc, agg, N_NODES);
    layer_kernel<4, true><<<LB, 256, 0, stream>>>(agg, h1, W2l, b2, W2r, out, N_NODES);
}

// Round 5
// 294.014 us; speedup vs baseline: 2.2520x; 2.2520x over previous
//
#include <hip/hip_runtime.h>
#include <math.h>

#define N_NODES 50000
#define D 128       // d_in == d_hid
#define D_OUT 64

typedef short bf16x8 __attribute__((ext_vector_type(8)));   // 8 bf16 (4 VGPR) MFMA frag
typedef float f32x4  __attribute__((ext_vector_type(4)));   // MFMA accumulator
typedef unsigned short u16x8 __attribute__((ext_vector_type(8)));

__device__ __forceinline__ unsigned short f_to_bf16(float f) {
    unsigned int u = __float_as_uint(f);
    u = (u + 0x7fffu + ((u >> 16) & 1u)) >> 16;   // RNE
    return (unsigned short)u;
}
__device__ __forceinline__ float bf16lo(unsigned int v) { return __uint_as_float(v << 16); }
__device__ __forceinline__ float bf16hi(unsigned int v) { return __uint_as_float(v & 0xffff0000u); }

// ---------------------------------------------------------------------------
// f32 -> bf16 converters
// ---------------------------------------------------------------------------
__global__ __launch_bounds__(256) void conv_x_kernel(
    const float* __restrict__ in, unsigned short* __restrict__ out, int n)
{
    int i = (blockIdx.x * 256 + threadIdx.x) * 8;
    if (i >= n) return;
    float4 v0 = *reinterpret_cast<const float4*>(in + i);
    float4 v1 = *reinterpret_cast<const float4*>(in + i + 4);
    u16x8 o;
    o[0] = f_to_bf16(v0.x); o[1] = f_to_bf16(v0.y);
    o[2] = f_to_bf16(v0.z); o[3] = f_to_bf16(v0.w);
    o[4] = f_to_bf16(v1.x); o[5] = f_to_bf16(v1.y);
    o[6] = f_to_bf16(v1.z); o[7] = f_to_bf16(v1.w);
    *reinterpret_cast<u16x8*>(out + i) = o;
}

// Packed W conversion: W1l@0, W1r@16384, W2l@32768, W2r@40960 (elems). 49152 total.
__global__ __launch_bounds__(256) void conv_w_kernel(
    const float* __restrict__ w1l, const float* __restrict__ w1r,
    const float* __restrict__ w2l, const float* __restrict__ w2r,
    unsigned short* __restrict__ out)
{
    int i = (blockIdx.x * 256 + threadIdx.x) * 8;   // 6144 threads -> 49152 elems
    const float* src; int off;
    if      (i < 16384) { src = w1l; off = 0; }
    else if (i < 32768) { src = w1r; off = 16384; }
    else if (i < 40960) { src = w2l; off = 32768; }
    else                { src = w2r; off = 40960; }
    int li = i - off;
    float4 v0 = *reinterpret_cast<const float4*>(src + li);
    float4 v1 = *reinterpret_cast<const float4*>(src + li + 4);
    u16x8 o;
    o[0] = f_to_bf16(v0.x); o[1] = f_to_bf16(v0.y);
    o[2] = f_to_bf16(v0.z); o[3] = f_to_bf16(v0.w);
    o[4] = f_to_bf16(v1.x); o[5] = f_to_bf16(v1.y);
    o[6] = f_to_bf16(v1.z); o[7] = f_to_bf16(v1.w);
    *reinterpret_cast<u16x8*>(out + i) = o;
}

// ---------------------------------------------------------------------------
// CSR build (unchanged from round 2 — known good)
// ---------------------------------------------------------------------------
__global__ __launch_bounds__(256) void hist_kernel(
    const int* __restrict__ dst, int* __restrict__ deg, int E)
{
    int e = blockIdx.x * blockDim.x + threadIdx.x;
    if (e < E) atomicAdd(&deg[dst[e]], 1);
}

__global__ __launch_bounds__(256) void scan_kernel(
    const int* __restrict__ deg, int* __restrict__ row_ptr, int n)
{
    __shared__ int sums[256];
    __shared__ int excl[256];
    const int t = threadIdx.x;
    const int chunk = (n + 255) / 256;
    const int start = t * chunk;
    const int end   = min(start + chunk, n);

    int s = 0;
    for (int i = start; i < end; ++i) s += deg[i];
    sums[t] = s;
    __syncthreads();

    if (t == 0) {
        int run = 0;
        for (int i = 0; i < 256; ++i) { excl[i] = run; run += sums[i]; }
        row_ptr[n] = run;
    }
    __syncthreads();

    int run = excl[t];
    for (int i = start; i < end; ++i) { row_ptr[i] = run; run += deg[i]; }
}

__global__ __launch_bounds__(256) void fill_kernel(
    const int* __restrict__ src, const int* __restrict__ dst,
    const int* __restrict__ row_ptr, int* __restrict__ cursor,
    int* __restrict__ esrc, int E)
{
    int e = blockIdx.x * blockDim.x + threadIdx.x;
    if (e >= E) return;
    int d = dst[e];
    int pos = atomicAdd(&cursor[d], 1);
    esrc[row_ptr[d] + pos] = src[e];
}

// ---------------------------------------------------------------------------
// Gather-aggregate (bf16 in / bf16 out): one 64-lane wave per node.
// Lane reads one uint (2 bf16) per neighbor row: 256 B/row coalesced.
// Accumulates f32, writes premeaned bf16 row.
// ---------------------------------------------------------------------------
__global__ __launch_bounds__(256) void gather_bf16_kernel(
    const unsigned short* __restrict__ xb,
    const int* __restrict__ row_ptr,
    const int* __restrict__ esrc,
    unsigned short* __restrict__ aggb,
    int n_nodes)
{
    int gtid = blockIdx.x * blockDim.x + threadIdx.x;
    int node = gtid >> 6;
    int lane = gtid & 63;
    if (node >= n_nodes) return;

    int beg = row_ptr[node];
    int end = row_ptr[node + 1];

    const unsigned int* x32 = reinterpret_cast<const unsigned int*>(xb);
    float ax = 0.f, ay = 0.f;
    int p = beg;
    for (; p + 1 < end; p += 2) {
        unsigned int v0 = x32[(size_t)esrc[p]     * 64 + lane];
        unsigned int v1 = x32[(size_t)esrc[p + 1] * 64 + lane];
        ax += bf16lo(v0) + bf16lo(v1);
        ay += bf16hi(v0) + bf16hi(v1);
    }
    if (p < end) {
        unsigned int v0 = x32[(size_t)esrc[p] * 64 + lane];
        ax += bf16lo(v0);
        ay += bf16hi(v0);
    }

    float inv = (end > beg) ? 1.0f / (float)(end - beg) : 0.0f;
    unsigned int o = (unsigned int)f_to_bf16(ax * inv)
                   | ((unsigned int)f_to_bf16(ay * inv) << 16);
    reinterpret_cast<unsigned int*>(aggb)[(size_t)node * 64 + lane] = o;
}

// ---------------------------------------------------------------------------
// Layer 1 via MFMA 16x16x32 bf16. One wave per 16-node tile (3125 blocks).
// D = A(16x32)·B(32x16): A-frag lane l holds A[l&15][(l>>4)*8+e] (16B load);
// B[k][j] = W[j][k] row-major -> B-frag lane l loads W[jt*16+(l&15)] k-slice.
// D: col = lane&15, row = (lane>>4)*4 + reg   [m89 verified mapping]
// h1 = relu(agg·W1l^T + b1 + x·W1r^T), stored bf16.
// ---------------------------------------------------------------------------
__global__ __launch_bounds__(64) void layer1_mfma_kernel(
    const unsigned short* __restrict__ aggb,
    const unsigned short* __restrict__ xb,
    const unsigned short* __restrict__ Wb,   // W1l@0, W1r@16384
    const float* __restrict__ b1,
    unsigned short* __restrict__ h1b)
{
    const int lane  = threadIdx.x;
    const int node0 = blockIdx.x * 16;
    const int c16   = lane & 15;    // A row / W row / D col
    const int kg    = lane >> 4;    // k-group 0..3

    bf16x8 a[2][4];
    {
        const unsigned short* A0 = aggb + (size_t)(node0 + c16) * D + kg * 8;
        const unsigned short* A1 = xb   + (size_t)(node0 + c16) * D + kg * 8;
#pragma unroll
        for (int kf = 0; kf < 4; ++kf) {
            a[0][kf] = *reinterpret_cast<const bf16x8*>(A0 + kf * 32);
            a[1][kf] = *reinterpret_cast<const bf16x8*>(A1 + kf * 32);
        }
    }
    const unsigned short* WL = Wb;
    const unsigned short* WR = Wb + 16384;

#pragma unroll 2
    for (int jt = 0; jt < 8; ++jt) {
        f32x4 acc = {0.f, 0.f, 0.f, 0.f};
        const unsigned short* wl = WL + (size_t)(jt * 16 + c16) * D + kg * 8;
        const unsigned short* wr = WR + (size_t)(jt * 16 + c16) * D + kg * 8;
#pragma unroll
        for (int kf = 0; kf < 4; ++kf) {
            bf16x8 b = *reinterpret_cast<const bf16x8*>(wl + kf * 32);
            acc = __builtin_amdgcn_mfma_f32_16x16x32_bf16(a[0][kf], b, acc, 0, 0, 0);
        }
#pragma unroll
        for (int kf = 0; kf < 4; ++kf) {
            bf16x8 b = *reinterpret_cast<const bf16x8*>(wr + kf * 32);
            acc = __builtin_amdgcn_mfma_f32_16x16x32_bf16(a[1][kf], b, acc, 0, 0, 0);
        }
        const float bias = b1[jt * 16 + c16];
#pragma unroll
        for (int i = 0; i < 4; ++i) {
            float v = fmaxf(acc[i] + bias, 0.0f);
            h1b[(size_t)(node0 + kg * 4 + i) * D + jt * 16 + c16] = f_to_bf16(v);
        }
    }
}

// ---------------------------------------------------------------------------
// Layer 2 via MFMA + fused log_softmax over 64 outputs.
// Same fragment scheme; 4 j-tiles kept in accumulators; softmax reduces
// 4 in-lane regs (jt) x 16 lanes (cols, shfl_xor 1/2/4/8 within the group).
// ---------------------------------------------------------------------------
__global__ __launch_bounds__(64) void layer2_mfma_kernel(
    const unsigned short* __restrict__ aggb,
    const unsigned short* __restrict__ h1b,
    const unsigned short* __restrict__ Wb,   // W2l@32768, W2r@40960
    const float* __restrict__ b2,
    float* __restrict__ out)
{
    const int lane  = threadIdx.x;
    const int node0 = blockIdx.x * 16;
    const int c16   = lane & 15;
    const int kg    = lane >> 4;

    bf16x8 a[2][4];
    {
        const unsigned short* A0 = aggb + (size_t)(node0 + c16) * D + kg * 8;
        const unsigned short* A1 = h1b  + (size_t)(node0 + c16) * D + kg * 8;
#pragma unroll
        for (int kf = 0; kf < 4; ++kf) {
            a[0][kf] = *reinterpret_cast<const bf16x8*>(A0 + kf * 32);
            a[1][kf] = *reinterpret_cast<const bf16x8*>(A1 + kf * 32);
        }
    }
    const unsigned short* WL = Wb + 32768;
    const unsigned short* WR = Wb + 40960;

    f32x4 accs[4];
#pragma unroll
    for (int jt = 0; jt < 4; ++jt) {
        f32x4 acc = {0.f, 0.f, 0.f, 0.f};
        const unsigned short* wl = WL + (size_t)(jt * 16 + c16) * D + kg * 8;
        const unsigned short* wr = WR + (size_t)(jt * 16 + c16) * D + kg * 8;
#pragma unroll
        for (int kf = 0; kf < 4; ++kf) {
            bf16x8 b = *reinterpret_cast<const bf16x8*>(wl + kf * 32);
            acc = __builtin_amdgcn_mfma_f32_16x16x32_bf16(a[0][kf], b, acc, 0, 0, 0);
        }
#pragma unroll
        for (int kf = 0; kf < 4; ++kf) {
            bf16x8 b = *reinterpret_cast<const bf16x8*>(wr + kf * 32);
            acc = __builtin_amdgcn_mfma_f32_16x16x32_bf16(a[1][kf], b, acc, 0, 0, 0);
        }
        accs[jt] = acc;
    }

    float bias[4];
#pragma unroll
    for (int jt = 0; jt < 4; ++jt) bias[jt] = b2[jt * 16 + c16];

#pragma unroll
    for (int i = 0; i < 4; ++i) {
        float z[4];
        float m = -1e30f;
#pragma unroll
        for (int jt = 0; jt < 4; ++jt) {
            z[jt] = accs[jt][i] + bias[jt];
            m = fmaxf(m, z[jt]);
        }
#pragma unroll
        for (int off = 1; off < 16; off <<= 1)
            m = fmaxf(m, __shfl_xor(m, off));
        float s = 0.f;
#pragma unroll
        for (int jt = 0; jt < 4; ++jt) s += expf(z[jt] - m);
#pragma unroll
        for (int off = 1; off < 16; off <<= 1)
            s += __shfl_xor(s, off);
        float lse = m + logf(s);
        const int node = node0 + kg * 4 + i;
#pragma unroll
        for (int jt = 0; jt < 4; ++jt)
            out[(size_t)node * D_OUT + jt * 16 + c16] = z[jt] - lse;
    }
}

// ---------------------------------------------------------------------------
extern "C" void kernel_launch(void* const* d_in, const int* in_sizes, int n_in,
                              void* d_out, int out_size, void* d_ws, size_t ws_size,
                              hipStream_t stream)
{
    const float* x   = (const float*)d_in[0];
    const int*   ei  = (const int*)d_in[1];
    const float* W1l = (const float*)d_in[2];
    const float* b1  = (const float*)d_in[3];
    const float* W1r = (const float*)d_in[4];
    const float* W2l = (const float*)d_in[5];
    const float* b2  = (const float*)d_in[6];
    const float* W2r = (const float*)d_in[7];
    float* out = (float*)d_out;

    const int E = in_sizes[1] / 2;
    const int* src = ei;
    const int* dst = ei + E;

    // ---- workspace layout (256B-aligned chunks) ----
    char* base = (char*)d_ws;
    size_t off = 0;
    auto take = [&](size_t bytes) { char* p = base + off; off += (bytes + 255) & ~(size_t)255; return p; };

    unsigned short* xb   = (unsigned short*)take((size_t)N_NODES * D * 2);   // 12.8 MB
    unsigned short* aggb = (unsigned short*)take((size_t)N_NODES * D * 2);   // 12.8 MB
    unsigned short* h1b  = (unsigned short*)take((size_t)N_NODES * D * 2);   // 12.8 MB
    unsigned short* Wb   = (unsigned short*)take((size_t)49152 * 2);         // 96 KB
    int* deg     = (int*)take((size_t)N_NODES * 4);
    int* row_ptr = (int*)take(((size_t)N_NODES + 1) * 4);
    int* cursor  = (int*)take((size_t)N_NODES * 4);
    int* esrc    = (int*)take((size_t)E * 4);

    const int EB = (E + 255) / 256;

    // ---- converts + CSR build ----
    hipMemsetAsync(deg,    0, (size_t)N_NODES * sizeof(int), stream);
    hipMemsetAsync(cursor, 0, (size_t)N_NODES * sizeof(int), stream);
    conv_x_kernel<<<(N_NODES * D / 8 + 255) / 256, 256, 0, stream>>>(x, xb, N_NODES * D);
    conv_w_kernel<<<24, 256, 0, stream>>>(W1l, W1r, W2l, W2r, Wb);
    hist_kernel<<<EB, 256, 0, stream>>>(dst, deg, E);
    scan_kernel<<<1, 256, 0, stream>>>(deg, row_ptr, N_NODES);
    fill_kernel<<<EB, 256, 0, stream>>>(src, dst, row_ptr, cursor, esrc, E);

    const int GB = (N_NODES * 64 + 255) / 256;   // gather: 1 wave per node
    const int MB = N_NODES / 16;                 // 3125 MFMA tiles, exact

    // ---- layer 1 ----
    gather_bf16_kernel<<<GB, 256, 0, stream>>>(xb, row_ptr, esrc, aggb, N_NODES);
    layer1_mfma_kernel<<<MB, 64, 0, stream>>>(aggb, xb, Wb, b1, h1b);

    // ---- layer 2 ----
    gather_bf16_kernel<<<GB, 256, 0, stream>>>(h1b, row_ptr, esrc, aggb, N_NODES);
    layer2_mfma_kernel<<<MB, 64, 0, stream>>>(aggb, h1b, Wb, b2, out);
}

// Round 6
// 212.485 us; speedup vs baseline: 3.1161x; 1.3837x over previous
//
#include <hip/hip_runtime.h>
#include <math.h>

#define N_NODES 50000
#define D 128       // d_in == d_hid
#define D_OUT 64

typedef short bf16x8 __attribute__((ext_vector_type(8)));   // 8 bf16 (4 VGPR) MFMA frag
typedef float f32x4  __attribute__((ext_vector_type(4)));   // MFMA accumulator
typedef unsigned short u16x8 __attribute__((ext_vector_type(8)));

__device__ __forceinline__ unsigned short f_to_bf16(float f) {
    unsigned int u = __float_as_uint(f);
    u = (u + 0x7fffu + ((u >> 16) & 1u)) >> 16;   // RNE
    return (unsigned short)u;
}
__device__ __forceinline__ float bf16lo(unsigned int v) { return __uint_as_float(v << 16); }
__device__ __forceinline__ float bf16hi(unsigned int v) { return __uint_as_float(v & 0xffff0000u); }

// ---------------------------------------------------------------------------
// f32 -> bf16 converters
// ---------------------------------------------------------------------------
__global__ __launch_bounds__(256) void conv_x_kernel(
    const float* __restrict__ in, unsigned short* __restrict__ out, int n)
{
    int i = (blockIdx.x * 256 + threadIdx.x) * 8;
    if (i >= n) return;
    float4 v0 = *reinterpret_cast<const float4*>(in + i);
    float4 v1 = *reinterpret_cast<const float4*>(in + i + 4);
    u16x8 o;
    o[0] = f_to_bf16(v0.x); o[1] = f_to_bf16(v0.y);
    o[2] = f_to_bf16(v0.z); o[3] = f_to_bf16(v0.w);
    o[4] = f_to_bf16(v1.x); o[5] = f_to_bf16(v1.y);
    o[6] = f_to_bf16(v1.z); o[7] = f_to_bf16(v1.w);
    *reinterpret_cast<u16x8*>(out + i) = o;
}

// Packed W conversion: W1l@0, W1r@16384, W2l@32768, W2r@40960 (elems). 49152 total.
__global__ __launch_bounds__(256) void conv_w_kernel(
    const float* __restrict__ w1l, const float* __restrict__ w1r,
    const float* __restrict__ w2l, const float* __restrict__ w2r,
    unsigned short* __restrict__ out)
{
    int i = (blockIdx.x * 256 + threadIdx.x) * 8;   // 6144 threads -> 49152 elems
    const float* src; int off;
    if      (i < 16384) { src = w1l; off = 0; }
    else if (i < 32768) { src = w1r; off = 16384; }
    else if (i < 40960) { src = w2l; off = 32768; }
    else                { src = w2r; off = 40960; }
    int li = i - off;
    float4 v0 = *reinterpret_cast<const float4*>(src + li);
    float4 v1 = *reinterpret_cast<const float4*>(src + li + 4);
    u16x8 o;
    o[0] = f_to_bf16(v0.x); o[1] = f_to_bf16(v0.y);
    o[2] = f_to_bf16(v0.z); o[3] = f_to_bf16(v0.w);
    o[4] = f_to_bf16(v1.x); o[5] = f_to_bf16(v1.y);
    o[6] = f_to_bf16(v1.z); o[7] = f_to_bf16(v1.w);
    *reinterpret_cast<u16x8*>(out + i) = o;
}

// ---------------------------------------------------------------------------
// CSR build step 1: in-degree histogram
// ---------------------------------------------------------------------------
__global__ __launch_bounds__(256) void hist_kernel(
    const int* __restrict__ dst, int* __restrict__ deg, int E)
{
    int e = blockIdx.x * blockDim.x + threadIdx.x;
    if (e < E) atomicAdd(&deg[dst[e]], 1);
}

// ---------------------------------------------------------------------------
// Hierarchical exclusive scan: scan1 (per-block, 1024 elems) -> scan2 (block
// sums, one wave) -> scan3 (add offsets).
// ---------------------------------------------------------------------------
__global__ __launch_bounds__(256) void scan1_kernel(
    const int* __restrict__ deg, int* __restrict__ part,
    int* __restrict__ bsum, int n)
{
    const int t = threadIdx.x;
    const int base = blockIdx.x * 1024 + t * 4;

    int a0 = 0, a1 = 0, a2 = 0, a3 = 0;
    if (base + 3 < n) {
        int4 v = *reinterpret_cast<const int4*>(deg + base);
        a0 = v.x; a1 = v.y; a2 = v.z; a3 = v.w;
    } else if (base < n) {
        a0 = deg[base];
        if (base + 1 < n) a1 = deg[base + 1];
        if (base + 2 < n) a2 = deg[base + 2];
    }
    const int s0 = a0, s1 = s0 + a1, s2 = s1 + a2, s3 = s2 + a3;

    const int lane = t & 63;
    int incl = s3;
#pragma unroll
    for (int off = 1; off < 64; off <<= 1) {
        int up = __shfl_up(incl, off);
        if (lane >= off) incl += up;
    }

    __shared__ int wsum[4];
    const int wid = t >> 6;
    if (lane == 63) wsum[wid] = incl;
    __syncthreads();

    int woff = 0;
#pragma unroll
    for (int w = 0; w < 4; ++w) woff += (w < wid) ? wsum[w] : 0;

    const int ex = woff + incl - s3;   // exclusive prefix of this thread's 1st elem
    if (base + 3 < n) {
        int4 o; o.x = ex; o.y = ex + s0; o.z = ex + s1; o.w = ex + s2;
        *reinterpret_cast<int4*>(part + base) = o;
    } else if (base < n) {
        part[base] = ex;
        if (base + 1 < n) part[base + 1] = ex + s0;
        if (base + 2 < n) part[base + 2] = ex + s1;
    }
    if (t == 255) bsum[blockIdx.x] = woff + incl;   // block total
}

__global__ __launch_bounds__(64) void scan2_kernel(
    int* __restrict__ bsum, int* __restrict__ row_ptr, int nb, int n)
{
    const int t = threadIdx.x;   // one wave; nb <= 64
    int v = (t < nb) ? bsum[t] : 0;
    int incl = v;
#pragma unroll
    for (int off = 1; off < 64; off <<= 1) {
        int up = __shfl_up(incl, off);
        if (t >= off) incl += up;
    }
    if (t < nb) bsum[t] = incl - v;    // exclusive
    if (t == 63) row_ptr[n] = incl;    // grand total = E
}

__global__ __launch_bounds__(256) void scan3_kernel(
    const int* __restrict__ part, const int* __restrict__ bsum,
    int* __restrict__ row_ptr, int n)
{
    const int base = blockIdx.x * 1024 + threadIdx.x * 4;
    const int add = bsum[blockIdx.x];
    if (base + 3 < n) {
        int4 v = *reinterpret_cast<const int4*>(part + base);
        v.x += add; v.y += add; v.z += add; v.w += add;
        *reinterpret_cast<int4*>(row_ptr + base) = v;
    } else if (base < n) {
        row_ptr[base] = part[base] + add;
        if (base + 1 < n) row_ptr[base + 1] = part[base + 1] + add;
        if (base + 2 < n) row_ptr[base + 2] = part[base + 2] + add;
    }
}

// ---------------------------------------------------------------------------
// CSR build step 3: bucket-fill edge sources (order within bucket arbitrary)
// ---------------------------------------------------------------------------
__global__ __launch_bounds__(256) void fill_kernel(
    const int* __restrict__ src, const int* __restrict__ dst,
    const int* __restrict__ row_ptr, int* __restrict__ cursor,
    int* __restrict__ esrc, int E)
{
    int e = blockIdx.x * blockDim.x + threadIdx.x;
    if (e >= E) return;
    int d = dst[e];
    int pos = atomicAdd(&cursor[d], 1);
    esrc[row_ptr[d] + pos] = src[e];
}

// ---------------------------------------------------------------------------
// Gather-aggregate (bf16 in / bf16 out): one 64-lane wave per node.
// ---------------------------------------------------------------------------
__global__ __launch_bounds__(256) void gather_bf16_kernel(
    const unsigned short* __restrict__ xb,
    const int* __restrict__ row_ptr,
    const int* __restrict__ esrc,
    unsigned short* __restrict__ aggb,
    int n_nodes)
{
    int gtid = blockIdx.x * blockDim.x + threadIdx.x;
    int node = gtid >> 6;
    int lane = gtid & 63;
    if (node >= n_nodes) return;

    int beg = row_ptr[node];
    int end = row_ptr[node + 1];

    const unsigned int* x32 = reinterpret_cast<const unsigned int*>(xb);
    float ax = 0.f, ay = 0.f;
    int p = beg;
    for (; p + 1 < end; p += 2) {
        unsigned int v0 = x32[(size_t)esrc[p]     * 64 + lane];
        unsigned int v1 = x32[(size_t)esrc[p + 1] * 64 + lane];
        ax += bf16lo(v0) + bf16lo(v1);
        ay += bf16hi(v0) + bf16hi(v1);
    }
    if (p < end) {
        unsigned int v0 = x32[(size_t)esrc[p] * 64 + lane];
        ax += bf16lo(v0);
        ay += bf16hi(v0);
    }

    float inv = (end > beg) ? 1.0f / (float)(end - beg) : 0.0f;
    unsigned int o = (unsigned int)f_to_bf16(ax * inv)
                   | ((unsigned int)f_to_bf16(ay * inv) << 16);
    reinterpret_cast<unsigned int*>(aggb)[(size_t)node * 64 + lane] = o;
}

// ---------------------------------------------------------------------------
// Layer 1 via MFMA 16x16x32 bf16. One wave per 16-node tile (3125 blocks).
// D: col = lane&15, row = (lane>>4)*4 + reg   [m89 verified mapping]
// ---------------------------------------------------------------------------
__global__ __launch_bounds__(64) void layer1_mfma_kernel(
    const unsigned short* __restrict__ aggb,
    const unsigned short* __restrict__ xb,
    const unsigned short* __restrict__ Wb,   // W1l@0, W1r@16384
    const float* __restrict__ b1,
    unsigned short* __restrict__ h1b)
{
    const int lane  = threadIdx.x;
    const int node0 = blockIdx.x * 16;
    const int c16   = lane & 15;    // A row / W row / D col
    const int kg    = lane >> 4;    // k-group 0..3

    bf16x8 a[2][4];
    {
        const unsigned short* A0 = aggb + (size_t)(node0 + c16) * D + kg * 8;
        const unsigned short* A1 = xb   + (size_t)(node0 + c16) * D + kg * 8;
#pragma unroll
        for (int kf = 0; kf < 4; ++kf) {
            a[0][kf] = *reinterpret_cast<const bf16x8*>(A0 + kf * 32);
            a[1][kf] = *reinterpret_cast<const bf16x8*>(A1 + kf * 32);
        }
    }
    const unsigned short* WL = Wb;
    const unsigned short* WR = Wb + 16384;

#pragma unroll 2
    for (int jt = 0; jt < 8; ++jt) {
        f32x4 acc = {0.f, 0.f, 0.f, 0.f};
        const unsigned short* wl = WL + (size_t)(jt * 16 + c16) * D + kg * 8;
        const unsigned short* wr = WR + (size_t)(jt * 16 + c16) * D + kg * 8;
#pragma unroll
        for (int kf = 0; kf < 4; ++kf) {
            bf16x8 b = *reinterpret_cast<const bf16x8*>(wl + kf * 32);
            acc = __builtin_amdgcn_mfma_f32_16x16x32_bf16(a[0][kf], b, acc, 0, 0, 0);
        }
#pragma unroll
        for (int kf = 0; kf < 4; ++kf) {
            bf16x8 b = *reinterpret_cast<const bf16x8*>(wr + kf * 32);
            acc = __builtin_amdgcn_mfma_f32_16x16x32_bf16(a[1][kf], b, acc, 0, 0, 0);
        }
        const float bias = b1[jt * 16 + c16];
#pragma unroll
        for (int i = 0; i < 4; ++i) {
            float v = fmaxf(acc[i] + bias, 0.0f);
            h1b[(size_t)(node0 + kg * 4 + i) * D + jt * 16 + c16] = f_to_bf16(v);
        }
    }
}

// ---------------------------------------------------------------------------
// Layer 2 via MFMA + fused log_softmax over 64 outputs.
// ---------------------------------------------------------------------------
__global__ __launch_bounds__(64) void layer2_mfma_kernel(
    const unsigned short* __restrict__ aggb,
    const unsigned short* __restrict__ h1b,
    const unsigned short* __restrict__ Wb,   // W2l@32768, W2r@40960
    const float* __restrict__ b2,
    float* __restrict__ out)
{
    const int lane  = threadIdx.x;
    const int node0 = blockIdx.x * 16;
    const int c16   = lane & 15;
    const int kg    = lane >> 4;

    bf16x8 a[2][4];
    {
        const unsigned short* A0 = aggb + (size_t)(node0 + c16) * D + kg * 8;
        const unsigned short* A1 = h1b  + (size_t)(node0 + c16) * D + kg * 8;
#pragma unroll
        for (int kf = 0; kf < 4; ++kf) {
            a[0][kf] = *reinterpret_cast<const bf16x8*>(A0 + kf * 32);
            a[1][kf] = *reinterpret_cast<const bf16x8*>(A1 + kf * 32);
        }
    }
    const unsigned short* WL = Wb + 32768;
    const unsigned short* WR = Wb + 40960;

    f32x4 accs[4];
#pragma unroll
    for (int jt = 0; jt < 4; ++jt) {
        f32x4 acc = {0.f, 0.f, 0.f, 0.f};
        const unsigned short* wl = WL + (size_t)(jt * 16 + c16) * D + kg * 8;
        const unsigned short* wr = WR + (size_t)(jt * 16 + c16) * D + kg * 8;
#pragma unroll
        for (int kf = 0; kf < 4; ++kf) {
            bf16x8 b = *reinterpret_cast<const bf16x8*>(wl + kf * 32);
            acc = __builtin_amdgcn_mfma_f32_16x16x32_bf16(a[0][kf], b, acc, 0, 0, 0);
        }
#pragma unroll
        for (int kf = 0; kf < 4; ++kf) {
            bf16x8 b = *reinterpret_cast<const bf16x8*>(wr + kf * 32);
            acc = __builtin_amdgcn_mfma_f32_16x16x32_bf16(a[1][kf], b, acc, 0, 0, 0);
        }
        accs[jt] = acc;
    }

    float bias[4];
#pragma unroll
    for (int jt = 0; jt < 4; ++jt) bias[jt] = b2[jt * 16 + c16];

#pragma unroll
    for (int i = 0; i < 4; ++i) {
        float z[4];
        float m = -1e30f;
#pragma unroll
        for (int jt = 0; jt < 4; ++jt) {
            z[jt] = accs[jt][i] + bias[jt];
            m = fmaxf(m, z[jt]);
        }
#pragma unroll
        for (int off = 1; off < 16; off <<= 1)
            m = fmaxf(m, __shfl_xor(m, off));
        float s = 0.f;
#pragma unroll
        for (int jt = 0; jt < 4; ++jt) s += expf(z[jt] - m);
#pragma unroll
        for (int off = 1; off < 16; off <<= 1)
            s += __shfl_xor(s, off);
        float lse = m + logf(s);
        const int node = node0 + kg * 4 + i;
#pragma unroll
        for (int jt = 0; jt < 4; ++jt)
            out[(size_t)node * D_OUT + jt * 16 + c16] = z[jt] - lse;
    }
}

// ---------------------------------------------------------------------------
extern "C" void kernel_launch(void* const* d_in, const int* in_sizes, int n_in,
                              void* d_out, int out_size, void* d_ws, size_t ws_size,
                              hipStream_t stream)
{
    const float* x   = (const float*)d_in[0];
    const int*   ei  = (const int*)d_in[1];
    const float* W1l = (const float*)d_in[2];
    const float* b1  = (const float*)d_in[3];
    const float* W1r = (const float*)d_in[4];
    const float* W2l = (const float*)d_in[5];
    const float* b2  = (const float*)d_in[6];
    const float* W2r = (const float*)d_in[7];
    float* out = (float*)d_out;

    const int E = in_sizes[1] / 2;
    const int* src = ei;
    const int* dst = ei + E;

    // ---- workspace layout (256B-aligned chunks) ----
    char* base = (char*)d_ws;
    size_t off = 0;
    auto take = [&](size_t bytes) { char* p = base + off; off += (bytes + 255) & ~(size_t)255; return p; };

    unsigned short* xb   = (unsigned short*)take((size_t)N_NODES * D * 2);   // 12.8 MB
    unsigned short* aggb = (unsigned short*)take((size_t)N_NODES * D * 2);   // 12.8 MB
    unsigned short* h1b  = (unsigned short*)take((size_t)N_NODES * D * 2);   // 12.8 MB
    unsigned short* Wb   = (unsigned short*)take((size_t)49152 * 2);         // 96 KB
    int* degcur  = (int*)take((size_t)2 * N_NODES * 4);   // deg | cursor (one memset)
    int* deg     = degcur;
    int* cursor  = degcur + N_NODES;
    int* row_ptr = (int*)take(((size_t)N_NODES + 1) * 4);
    int* part    = (int*)take((size_t)N_NODES * 4);
    int* bsum    = (int*)take((size_t)64 * 4);
    int* esrc    = (int*)take((size_t)E * 4);

    const int EB = (E + 255) / 256;
    const int SB = (N_NODES + 1023) / 1024;      // 49 scan blocks

    // ---- converts + CSR build ----
    hipMemsetAsync(degcur, 0, (size_t)2 * N_NODES * sizeof(int), stream);
    conv_x_kernel<<<(N_NODES * D / 8 + 255) / 256, 256, 0, stream>>>(x, xb, N_NODES * D);
    conv_w_kernel<<<24, 256, 0, stream>>>(W1l, W1r, W2l, W2r, Wb);
    hist_kernel<<<EB, 256, 0, stream>>>(dst, deg, E);
    scan1_kernel<<<SB, 256, 0, stream>>>(deg, part, bsum, N_NODES);
    scan2_kernel<<<1, 64, 0, stream>>>(bsum, row_ptr, SB, N_NODES);
    scan3_kernel<<<SB, 256, 0, stream>>>(part, bsum, row_ptr, N_NODES);
    fill_kernel<<<EB, 256, 0, stream>>>(src, dst, row_ptr, cursor, esrc, E);

    const int GB = (N_NODES * 64 + 255) / 256;   // gather: 1 wave per node
    const int MB = N_NODES / 16;                 // 3125 MFMA tiles, exact

    // ---- layer 1 ----
    gather_bf16_kernel<<<GB, 256, 0, stream>>>(xb, row_ptr, esrc, aggb, N_NODES);
    layer1_mfma_kernel<<<MB, 64, 0, stream>>>(aggb, xb, Wb, b1, h1b);

    // ---- layer 2 ----
    gather_bf16_kernel<<<GB, 256, 0, stream>>>(h1b, row_ptr, esrc, aggb, N_NODES);
    layer2_mfma_kernel<<<MB, 64, 0, stream>>>(aggb, h1b, Wb, b2, out);
}

// Round 7
// 197.777 us; speedup vs baseline: 3.3478x; 1.0744x over previous
//
#include <hip/hip_runtime.h>
#include <math.h>

#define N_NODES 50000
#define D 128       // d_in == d_hid
#define D_OUT 64

typedef short bf16x8 __attribute__((ext_vector_type(8)));   // 8 bf16 (4 VGPR) MFMA frag
typedef float f32x4  __attribute__((ext_vector_type(4)));   // MFMA accumulator
typedef unsigned short u16x8 __attribute__((ext_vector_type(8)));

__device__ __forceinline__ unsigned short f_to_bf16(float f) {
    unsigned int u = __float_as_uint(f);
    u = (u + 0x7fffu + ((u >> 16) & 1u)) >> 16;   // RNE
    return (unsigned short)u;
}
__device__ __forceinline__ float bf16lo(unsigned int v) { return __uint_as_float(v << 16); }
__device__ __forceinline__ float bf16hi(unsigned int v) { return __uint_as_float(v & 0xffff0000u); }

__device__ __forceinline__ void conv8(const float* __restrict__ src, unsigned short* __restrict__ dst, int i)
{
    float4 v0 = *reinterpret_cast<const float4*>(src + i);
    float4 v1 = *reinterpret_cast<const float4*>(src + i + 4);
    u16x8 o;
    o[0] = f_to_bf16(v0.x); o[1] = f_to_bf16(v0.y);
    o[2] = f_to_bf16(v0.z); o[3] = f_to_bf16(v0.w);
    o[4] = f_to_bf16(v1.x); o[5] = f_to_bf16(v1.y);
    o[6] = f_to_bf16(v1.z); o[7] = f_to_bf16(v1.w);
    *reinterpret_cast<u16x8*>(dst + i) = o;
}

// ---------------------------------------------------------------------------
// Zero deg|cursor (replaces 41us fillBufferAligned): 2*N ints, int4/thread.
// ---------------------------------------------------------------------------
__global__ __launch_bounds__(256) void zero_kernel(int* __restrict__ p, int n4)
{
    int i = blockIdx.x * 256 + threadIdx.x;
    if (i < n4) *reinterpret_cast<int4*>(p + i * 4) = make_int4(0, 0, 0, 0);
}

// ---------------------------------------------------------------------------
// Fused prep: conv_x | conv_w | hist, dispatched by block range.
// XB=3125 conv_x blocks, 24 conv_w blocks, EB hist blocks.
// ---------------------------------------------------------------------------
__global__ __launch_bounds__(256) void prep_kernel(
    const float* __restrict__ x, unsigned short* __restrict__ xb,
    const float* __restrict__ w1l, const float* __restrict__ w1r,
    const float* __restrict__ w2l, const float* __restrict__ w2r,
    unsigned short* __restrict__ Wb,
    const int* __restrict__ dst, int* __restrict__ deg,
    int XB, int E)
{
    const int bx = blockIdx.x;
    if (bx < XB) {
        int i = (bx * 256 + threadIdx.x) * 8;
        if (i < N_NODES * D) conv8(x, xb, i);
    } else if (bx < XB + 24) {
        int i = ((bx - XB) * 256 + threadIdx.x) * 8;   // 49152 elems
        const float* src; int off;
        if      (i < 16384) { src = w1l; off = 0; }
        else if (i < 32768) { src = w1r; off = 16384; }
        else if (i < 40960) { src = w2l; off = 32768; }
        else                { src = w2r; off = 40960; }
        conv8(src, Wb + off, i - off);   // note: conv8 indexes src+li, dst+li
    } else {
        int e = (bx - XB - 24) * 256 + threadIdx.x;
        if (e < E) atomicAdd(&deg[dst[e]], 1);
    }
}

// ---------------------------------------------------------------------------
// Hierarchical exclusive scan
// ---------------------------------------------------------------------------
__global__ __launch_bounds__(256) void scan1_kernel(
    const int* __restrict__ deg, int* __restrict__ part,
    int* __restrict__ bsum, int n)
{
    const int t = threadIdx.x;
    const int base = blockIdx.x * 1024 + t * 4;

    int a0 = 0, a1 = 0, a2 = 0, a3 = 0;
    if (base + 3 < n) {
        int4 v = *reinterpret_cast<const int4*>(deg + base);
        a0 = v.x; a1 = v.y; a2 = v.z; a3 = v.w;
    } else if (base < n) {
        a0 = deg[base];
        if (base + 1 < n) a1 = deg[base + 1];
        if (base + 2 < n) a2 = deg[base + 2];
    }
    const int s0 = a0, s1 = s0 + a1, s2 = s1 + a2, s3 = s2 + a3;

    const int lane = t & 63;
    int incl = s3;
#pragma unroll
    for (int off = 1; off < 64; off <<= 1) {
        int up = __shfl_up(incl, off);
        if (lane >= off) incl += up;
    }

    __shared__ int wsum[4];
    const int wid = t >> 6;
    if (lane == 63) wsum[wid] = incl;
    __syncthreads();

    int woff = 0;
#pragma unroll
    for (int w = 0; w < 4; ++w) woff += (w < wid) ? wsum[w] : 0;

    const int ex = woff + incl - s3;
    if (base + 3 < n) {
        int4 o; o.x = ex; o.y = ex + s0; o.z = ex + s1; o.w = ex + s2;
        *reinterpret_cast<int4*>(part + base) = o;
    } else if (base < n) {
        part[base] = ex;
        if (base + 1 < n) part[base + 1] = ex + s0;
        if (base + 2 < n) part[base + 2] = ex + s1;
    }
    if (t == 255) bsum[blockIdx.x] = woff + incl;
}

__global__ __launch_bounds__(64) void scan2_kernel(
    int* __restrict__ bsum, int* __restrict__ row_ptr, int nb, int n)
{
    const int t = threadIdx.x;
    int v = (t < nb) ? bsum[t] : 0;
    int incl = v;
#pragma unroll
    for (int off = 1; off < 64; off <<= 1) {
        int up = __shfl_up(incl, off);
        if (t >= off) incl += up;
    }
    if (t < nb) bsum[t] = incl - v;
    if (t == 63) row_ptr[n] = incl;
}

__global__ __launch_bounds__(256) void scan3_kernel(
    const int* __restrict__ part, const int* __restrict__ bsum,
    int* __restrict__ row_ptr, int n)
{
    const int base = blockIdx.x * 1024 + threadIdx.x * 4;
    const int add = bsum[blockIdx.x];
    if (base + 3 < n) {
        int4 v = *reinterpret_cast<const int4*>(part + base);
        v.x += add; v.y += add; v.z += add; v.w += add;
        *reinterpret_cast<int4*>(row_ptr + base) = v;
    } else if (base < n) {
        row_ptr[base] = part[base] + add;
        if (base + 1 < n) row_ptr[base + 1] = part[base + 1] + add;
        if (base + 2 < n) row_ptr[base + 2] = part[base + 2] + add;
    }
}

// ---------------------------------------------------------------------------
// CSR bucket-fill
// ---------------------------------------------------------------------------
__global__ __launch_bounds__(256) void fill_kernel(
    const int* __restrict__ src, const int* __restrict__ dst,
    const int* __restrict__ row_ptr, int* __restrict__ cursor,
    int* __restrict__ esrc, int E)
{
    int e = blockIdx.x * blockDim.x + threadIdx.x;
    if (e >= E) return;
    int d = dst[e];
    int pos = atomicAdd(&cursor[d], 1);
    esrc[row_ptr[d] + pos] = src[e];
}

// ---------------------------------------------------------------------------
// Gather-aggregate: 1 wave/node, unroll-4 (4 row loads in flight per lane).
// ---------------------------------------------------------------------------
__global__ __launch_bounds__(256) void gather_bf16_kernel(
    const unsigned short* __restrict__ xb,
    const int* __restrict__ row_ptr,
    const int* __restrict__ esrc,
    unsigned short* __restrict__ aggb,
    int n_nodes)
{
    int gtid = blockIdx.x * blockDim.x + threadIdx.x;
    int node = gtid >> 6;
    int lane = gtid & 63;
    if (node >= n_nodes) return;

    int beg = row_ptr[node];
    int end = row_ptr[node + 1];

    const unsigned int* x32 = reinterpret_cast<const unsigned int*>(xb);
    float ax0 = 0.f, ay0 = 0.f, ax1 = 0.f, ay1 = 0.f;
    float ax2 = 0.f, ay2 = 0.f, ax3 = 0.f, ay3 = 0.f;
    int p = beg;
    for (; p + 3 < end; p += 4) {
        unsigned int v0 = x32[(size_t)esrc[p]     * 64 + lane];
        unsigned int v1 = x32[(size_t)esrc[p + 1] * 64 + lane];
        unsigned int v2 = x32[(size_t)esrc[p + 2] * 64 + lane];
        unsigned int v3 = x32[(size_t)esrc[p + 3] * 64 + lane];
        ax0 += bf16lo(v0); ay0 += bf16hi(v0);
        ax1 += bf16lo(v1); ay1 += bf16hi(v1);
        ax2 += bf16lo(v2); ay2 += bf16hi(v2);
        ax3 += bf16lo(v3); ay3 += bf16hi(v3);
    }
    for (; p < end; ++p) {
        unsigned int v = x32[(size_t)esrc[p] * 64 + lane];
        ax0 += bf16lo(v); ay0 += bf16hi(v);
    }
    float ax = (ax0 + ax1) + (ax2 + ax3);
    float ay = (ay0 + ay1) + (ay2 + ay3);

    float inv = (end > beg) ? 1.0f / (float)(end - beg) : 0.0f;
    unsigned int o = (unsigned int)f_to_bf16(ax * inv)
                   | ((unsigned int)f_to_bf16(ay * inv) << 16);
    reinterpret_cast<unsigned int*>(aggb)[(size_t)node * 64 + lane] = o;
}

// ---------------------------------------------------------------------------
// Layer 1 via MFMA 16x16x32 bf16. One wave per 16-node tile (3125 blocks).
// D: col = lane&15, row = (lane>>4)*4 + reg   [m89 verified mapping]
// ---------------------------------------------------------------------------
__global__ __launch_bounds__(64) void layer1_mfma_kernel(
    const unsigned short* __restrict__ aggb,
    const unsigned short* __restrict__ xb,
    const unsigned short* __restrict__ Wb,   // W1l@0, W1r@16384
    const float* __restrict__ b1,
    unsigned short* __restrict__ h1b)
{
    const int lane  = threadIdx.x;
    const int node0 = blockIdx.x * 16;
    const int c16   = lane & 15;
    const int kg    = lane >> 4;

    bf16x8 a[2][4];
    {
        const unsigned short* A0 = aggb + (size_t)(node0 + c16) * D + kg * 8;
        const unsigned short* A1 = xb   + (size_t)(node0 + c16) * D + kg * 8;
#pragma unroll
        for (int kf = 0; kf < 4; ++kf) {
            a[0][kf] = *reinterpret_cast<const bf16x8*>(A0 + kf * 32);
            a[1][kf] = *reinterpret_cast<const bf16x8*>(A1 + kf * 32);
        }
    }
    const unsigned short* WL = Wb;
    const unsigned short* WR = Wb + 16384;

#pragma unroll 2
    for (int jt = 0; jt < 8; ++jt) {
        f32x4 acc = {0.f, 0.f, 0.f, 0.f};
        const unsigned short* wl = WL + (size_t)(jt * 16 + c16) * D + kg * 8;
        const unsigned short* wr = WR + (size_t)(jt * 16 + c16) * D + kg * 8;
#pragma unroll
        for (int kf = 0; kf < 4; ++kf) {
            bf16x8 b = *reinterpret_cast<const bf16x8*>(wl + kf * 32);
            acc = __builtin_amdgcn_mfma_f32_16x16x32_bf16(a[0][kf], b, acc, 0, 0, 0);
        }
#pragma unroll
        for (int kf = 0; kf < 4; ++kf) {
            bf16x8 b = *reinterpret_cast<const bf16x8*>(wr + kf * 32);
            acc = __builtin_amdgcn_mfma_f32_16x16x32_bf16(a[1][kf], b, acc, 0, 0, 0);
        }
        const float bias = b1[jt * 16 + c16];
#pragma unroll
        for (int i = 0; i < 4; ++i) {
            float v = fmaxf(acc[i] + bias, 0.0f);
            h1b[(size_t)(node0 + kg * 4 + i) * D + jt * 16 + c16] = f_to_bf16(v);
        }
    }
}

// ---------------------------------------------------------------------------
// Layer 2 via MFMA + fused log_softmax over 64 outputs.
// ---------------------------------------------------------------------------
__global__ __launch_bounds__(64) void layer2_mfma_kernel(
    const unsigned short* __restrict__ aggb,
    const unsigned short* __restrict__ h1b,
    const unsigned short* __restrict__ Wb,   // W2l@32768, W2r@40960
    const float* __restrict__ b2,
    float* __restrict__ out)
{
    const int lane  = threadIdx.x;
    const int node0 = blockIdx.x * 16;
    const int c16   = lane & 15;
    const int kg    = lane >> 4;

    bf16x8 a[2][4];
    {
        const unsigned short* A0 = aggb + (size_t)(node0 + c16) * D + kg * 8;
        const unsigned short* A1 = h1b  + (size_t)(node0 + c16) * D + kg * 8;
#pragma unroll
        for (int kf = 0; kf < 4; ++kf) {
            a[0][kf] = *reinterpret_cast<const bf16x8*>(A0 + kf * 32);
            a[1][kf] = *reinterpret_cast<const bf16x8*>(A1 + kf * 32);
        }
    }
    const unsigned short* WL = Wb + 32768;
    const unsigned short* WR = Wb + 40960;

    f32x4 accs[4];
#pragma unroll
    for (int jt = 0; jt < 4; ++jt) {
        f32x4 acc = {0.f, 0.f, 0.f, 0.f};
        const unsigned short* wl = WL + (size_t)(jt * 16 + c16) * D + kg * 8;
        const unsigned short* wr = WR + (size_t)(jt * 16 + c16) * D + kg * 8;
#pragma unroll
        for (int kf = 0; kf < 4; ++kf) {
            bf16x8 b = *reinterpret_cast<const bf16x8*>(wl + kf * 32);
            acc = __builtin_amdgcn_mfma_f32_16x16x32_bf16(a[0][kf], b, acc, 0, 0, 0);
        }
#pragma unroll
        for (int kf = 0; kf < 4; ++kf) {
            bf16x8 b = *reinterpret_cast<const bf16x8*>(wr + kf * 32);
            acc = __builtin_amdgcn_mfma_f32_16x16x32_bf16(a[1][kf], b, acc, 0, 0, 0);
        }
        accs[jt] = acc;
    }

    float bias[4];
#pragma unroll
    for (int jt = 0; jt < 4; ++jt) bias[jt] = b2[jt * 16 + c16];

#pragma unroll
    for (int i = 0; i < 4; ++i) {
        float z[4];
        float m = -1e30f;
#pragma unroll
        for (int jt = 0; jt < 4; ++jt) {
            z[jt] = accs[jt][i] + bias[jt];
            m = fmaxf(m, z[jt]);
        }
#pragma unroll
        for (int off = 1; off < 16; off <<= 1)
            m = fmaxf(m, __shfl_xor(m, off));
        float s = 0.f;
#pragma unroll
        for (int jt = 0; jt < 4; ++jt) s += expf(z[jt] - m);
#pragma unroll
        for (int off = 1; off < 16; off <<= 1)
            s += __shfl_xor(s, off);
        float lse = m + logf(s);
        const int node = node0 + kg * 4 + i;
#pragma unroll
        for (int jt = 0; jt < 4; ++jt)
            out[(size_t)node * D_OUT + jt * 16 + c16] = z[jt] - lse;
    }
}

// ---------------------------------------------------------------------------
extern "C" void kernel_launch(void* const* d_in, const int* in_sizes, int n_in,
                              void* d_out, int out_size, void* d_ws, size_t ws_size,
                              hipStream_t stream)
{
    const float* x   = (const float*)d_in[0];
    const int*   ei  = (const int*)d_in[1];
    const float* W1l = (const float*)d_in[2];
    const float* b1  = (const float*)d_in[3];
    const float* W1r = (const float*)d_in[4];
    const float* W2l = (const float*)d_in[5];
    const float* b2  = (const float*)d_in[6];
    const float* W2r = (const float*)d_in[7];
    float* out = (float*)d_out;

    const int E = in_sizes[1] / 2;
    const int* src = ei;
    const int* dst = ei + E;

    // ---- workspace layout (256B-aligned chunks) ----
    char* base = (char*)d_ws;
    size_t off = 0;
    auto take = [&](size_t bytes) { char* p = base + off; off += (bytes + 255) & ~(size_t)255; return p; };

    unsigned short* xb   = (unsigned short*)take((size_t)N_NODES * D * 2);
    unsigned short* aggb = (unsigned short*)take((size_t)N_NODES * D * 2);
    unsigned short* h1b  = (unsigned short*)take((size_t)N_NODES * D * 2);
    unsigned short* Wb   = (unsigned short*)take((size_t)49152 * 2);
    int* degcur  = (int*)take((size_t)2 * N_NODES * 4);   // deg | cursor
    int* deg     = degcur;
    int* cursor  = degcur + N_NODES;
    int* row_ptr = (int*)take(((size_t)N_NODES + 1) * 4);
    int* part    = (int*)take((size_t)N_NODES * 4);
    int* bsum    = (int*)take((size_t)64 * 4);
    int* esrc    = (int*)take((size_t)E * 4);

    const int EB = (E + 255) / 256;
    const int SB = (N_NODES + 1023) / 1024;      // 49 scan blocks
    const int XB = (N_NODES * D / 8 + 255) / 256; // 3125 conv_x blocks

    // ---- zero + fused prep (conv_x | conv_w | hist) + scan + fill ----
    zero_kernel<<<(2 * N_NODES / 4 + 255) / 256, 256, 0, stream>>>(degcur, 2 * N_NODES / 4);
    prep_kernel<<<XB + 24 + EB, 256, 0, stream>>>(x, xb, W1l, W1r, W2l, W2r, Wb, dst, deg, XB, E);
    scan1_kernel<<<SB, 256, 0, stream>>>(deg, part, bsum, N_NODES);
    scan2_kernel<<<1, 64, 0, stream>>>(bsum, row_ptr, SB, N_NODES);
    scan3_kernel<<<SB, 256, 0, stream>>>(part, bsum, row_ptr, N_NODES);
    fill_kernel<<<EB, 256, 0, stream>>>(src, dst, row_ptr, cursor, esrc, E);

    const int GB = (N_NODES * 64 + 255) / 256;   // gather: 1 wave per node
    const int MB = N_NODES / 16;                 // 3125 MFMA tiles, exact

    // ---- layer 1 ----
    gather_bf16_kernel<<<GB, 256, 0, stream>>>(xb, row_ptr, esrc, aggb, N_NODES);
    layer1_mfma_kernel<<<MB, 64, 0, stream>>>(aggb, xb, Wb, b1, h1b);

    // ---- layer 2 ----
    gather_bf16_kernel<<<GB, 256, 0, stream>>>(h1b, row_ptr, esrc, aggb, N_NODES);
    layer2_mfma_kernel<<<MB, 64, 0, stream>>>(aggb, h1b, Wb, b2, out);
}

// Round 8
// 173.544 us; speedup vs baseline: 3.8153x; 1.1396x over previous
//
#include <hip/hip_runtime.h>
#include <math.h>

#define N_NODES 50000
#define D 128       // d_in == d_hid
#define D_OUT 64

typedef short bf16x8 __attribute__((ext_vector_type(8)));   // 8 bf16 (4 VGPR) MFMA frag
typedef float f32x4  __attribute__((ext_vector_type(4)));   // MFMA accumulator
typedef unsigned short u16x8 __attribute__((ext_vector_type(8)));

__device__ __forceinline__ unsigned short f_to_bf16(float f) {
    unsigned int u = __float_as_uint(f);
    u = (u + 0x7fffu + ((u >> 16) & 1u)) >> 16;   // RNE
    return (unsigned short)u;
}
__device__ __forceinline__ float bf16lo(unsigned int v) { return __uint_as_float(v << 16); }
__device__ __forceinline__ float bf16hi(unsigned int v) { return __uint_as_float(v & 0xffff0000u); }

__device__ __forceinline__ void conv8(const float* __restrict__ src, unsigned short* __restrict__ dst, int i)
{
    float4 v0 = *reinterpret_cast<const float4*>(src + i);
    float4 v1 = *reinterpret_cast<const float4*>(src + i + 4);
    u16x8 o;
    o[0] = f_to_bf16(v0.x); o[1] = f_to_bf16(v0.y);
    o[2] = f_to_bf16(v0.z); o[3] = f_to_bf16(v0.w);
    o[4] = f_to_bf16(v1.x); o[5] = f_to_bf16(v1.y);
    o[6] = f_to_bf16(v1.z); o[7] = f_to_bf16(v1.w);
    *reinterpret_cast<u16x8*>(dst + i) = o;
}

__device__ __forceinline__ void acc_add(float* acc, uint4 v)
{
    acc[0] += bf16lo(v.x); acc[1] += bf16hi(v.x);
    acc[2] += bf16lo(v.y); acc[3] += bf16hi(v.y);
    acc[4] += bf16lo(v.z); acc[5] += bf16hi(v.z);
    acc[6] += bf16lo(v.w); acc[7] += bf16hi(v.w);
}

// ---------------------------------------------------------------------------
// Zero deg|cursor
// ---------------------------------------------------------------------------
__global__ __launch_bounds__(256) void zero_kernel(int* __restrict__ p, int n4)
{
    int i = blockIdx.x * 256 + threadIdx.x;
    if (i < n4) *reinterpret_cast<int4*>(p + i * 4) = make_int4(0, 0, 0, 0);
}

// ---------------------------------------------------------------------------
// Fused prep: conv_x | conv_w | hist, dispatched by block range.
// ---------------------------------------------------------------------------
__global__ __launch_bounds__(256) void prep_kernel(
    const float* __restrict__ x, unsigned short* __restrict__ xb,
    const float* __restrict__ w1l, const float* __restrict__ w1r,
    const float* __restrict__ w2l, const float* __restrict__ w2r,
    unsigned short* __restrict__ Wb,
    const int* __restrict__ dst, int* __restrict__ deg,
    int XB, int E)
{
    const int bx = blockIdx.x;
    if (bx < XB) {
        int i = (bx * 256 + threadIdx.x) * 8;
        if (i < N_NODES * D) conv8(x, xb, i);
    } else if (bx < XB + 24) {
        int i = ((bx - XB) * 256 + threadIdx.x) * 8;   // 49152 elems
        const float* src; int off;
        if      (i < 16384) { src = w1l; off = 0; }
        else if (i < 32768) { src = w1r; off = 16384; }
        else if (i < 40960) { src = w2l; off = 32768; }
        else                { src = w2r; off = 40960; }
        conv8(src, Wb + off, i - off);
    } else {
        int e = (bx - XB - 24) * 256 + threadIdx.x;
        if (e < E) atomicAdd(&deg[dst[e]], 1);
    }
}

// ---------------------------------------------------------------------------
// Hierarchical exclusive scan
// ---------------------------------------------------------------------------
__global__ __launch_bounds__(256) void scan1_kernel(
    const int* __restrict__ deg, int* __restrict__ part,
    int* __restrict__ bsum, int n)
{
    const int t = threadIdx.x;
    const int base = blockIdx.x * 1024 + t * 4;

    int a0 = 0, a1 = 0, a2 = 0, a3 = 0;
    if (base + 3 < n) {
        int4 v = *reinterpret_cast<const int4*>(deg + base);
        a0 = v.x; a1 = v.y; a2 = v.z; a3 = v.w;
    } else if (base < n) {
        a0 = deg[base];
        if (base + 1 < n) a1 = deg[base + 1];
        if (base + 2 < n) a2 = deg[base + 2];
    }
    const int s0 = a0, s1 = s0 + a1, s2 = s1 + a2, s3 = s2 + a3;

    const int lane = t & 63;
    int incl = s3;
#pragma unroll
    for (int off = 1; off < 64; off <<= 1) {
        int up = __shfl_up(incl, off);
        if (lane >= off) incl += up;
    }

    __shared__ int wsum[4];
    const int wid = t >> 6;
    if (lane == 63) wsum[wid] = incl;
    __syncthreads();

    int woff = 0;
#pragma unroll
    for (int w = 0; w < 4; ++w) woff += (w < wid) ? wsum[w] : 0;

    const int ex = woff + incl - s3;
    if (base + 3 < n) {
        int4 o; o.x = ex; o.y = ex + s0; o.z = ex + s1; o.w = ex + s2;
        *reinterpret_cast<int4*>(part + base) = o;
    } else if (base < n) {
        part[base] = ex;
        if (base + 1 < n) part[base + 1] = ex + s0;
        if (base + 2 < n) part[base + 2] = ex + s1;
    }
    if (t == 255) bsum[blockIdx.x] = woff + incl;
}

__global__ __launch_bounds__(64) void scan2_kernel(
    int* __restrict__ bsum, int* __restrict__ row_ptr, int nb, int n)
{
    const int t = threadIdx.x;
    int v = (t < nb) ? bsum[t] : 0;
    int incl = v;
#pragma unroll
    for (int off = 1; off < 64; off <<= 1) {
        int up = __shfl_up(incl, off);
        if (t >= off) incl += up;
    }
    if (t < nb) bsum[t] = incl - v;
    if (t == 63) row_ptr[n] = incl;
}

__global__ __launch_bounds__(256) void scan3_kernel(
    const int* __restrict__ part, const int* __restrict__ bsum,
    int* __restrict__ row_ptr, int n)
{
    const int base = blockIdx.x * 1024 + threadIdx.x * 4;
    const int add = bsum[blockIdx.x];
    if (base + 3 < n) {
        int4 v = *reinterpret_cast<const int4*>(part + base);
        v.x += add; v.y += add; v.z += add; v.w += add;
        *reinterpret_cast<int4*>(row_ptr + base) = v;
    } else if (base < n) {
        row_ptr[base] = part[base] + add;
        if (base + 1 < n) row_ptr[base + 1] = part[base + 1] + add;
        if (base + 2 < n) row_ptr[base + 2] = part[base + 2] + add;
    }
}

// ---------------------------------------------------------------------------
// CSR bucket-fill
// ---------------------------------------------------------------------------
__global__ __launch_bounds__(256) void fill_kernel(
    const int* __restrict__ src, const int* __restrict__ dst,
    const int* __restrict__ row_ptr, int* __restrict__ cursor,
    int* __restrict__ esrc, int E)
{
    int e = blockIdx.x * blockDim.x + threadIdx.x;
    if (e >= E) return;
    int d = dst[e];
    int pos = atomicAdd(&cursor[d], 1);
    esrc[row_ptr[d] + pos] = src[e];
}

// ---------------------------------------------------------------------------
// Gather-aggregate v3: 1 wave/node, 4 waves/block.
//  - lane-parallel esrc prefetch (1 load per <=64 neighbors), indices
//    broadcast from registers via __shfl (no index-load chain)
//  - 4 rows per load instr: lane group g (16 lanes) reads row p+g as uint4
//  - manual 2x unroll -> 8 rows in flight
//  - cross-group reduce via shfl_xor(16,32); group 0 writes premeaned row
// ---------------------------------------------------------------------------
__global__ __launch_bounds__(256) void gather_bf16_kernel(
    const unsigned short* __restrict__ xb,
    const int* __restrict__ row_ptr,
    const int* __restrict__ esrc,
    unsigned short* __restrict__ aggb,
    int n_nodes)
{
    const int wv   = threadIdx.x >> 6;
    const int lane = threadIdx.x & 63;
    const int node = blockIdx.x * 4 + wv;
    if (node >= n_nodes) return;

    const int beg = row_ptr[node];
    const int end = row_ptr[node + 1];
    const int g = lane >> 4;    // row slot within quad
    const int c = lane & 15;    // 16B column chunk (16 x 16B = 256B row)

    const uint4* x4 = reinterpret_cast<const uint4*>(xb);

    float acc[8];
#pragma unroll
    for (int k = 0; k < 8; ++k) acc[k] = 0.f;

    for (int base = beg; base < end; base += 64) {
        const int cnt = min(end - base, 64);
        int s = (base + lane < end) ? esrc[base + lane] : 0;
        for (int i = 0; i < cnt; i += 8) {
            const int p0 = i + g;
            const int p1 = i + 4 + g;
            const int s0 = __shfl(s, p0 & 63);
            const int s1 = __shfl(s, p1 & 63);
            // loads always safe (s0/s1 are valid node ids); mask contribution
            uint4 v0 = x4[(size_t)s0 * 16 + c];
            uint4 v1 = x4[(size_t)s1 * 16 + c];
            if (p0 < cnt) acc_add(acc, v0);
            if (p1 < cnt) acc_add(acc, v1);
        }
    }

    // combine the 4 row-slot groups (lanes c, c+16, c+32, c+48 share a chunk)
#pragma unroll
    for (int k = 0; k < 8; ++k) {
        acc[k] += __shfl_xor(acc[k], 16);
        acc[k] += __shfl_xor(acc[k], 32);
    }

    if (g == 0) {
        const float inv = (end > beg) ? 1.0f / (float)(end - beg) : 0.0f;
        uint4 o;
        o.x = (unsigned int)f_to_bf16(acc[0] * inv) | ((unsigned int)f_to_bf16(acc[1] * inv) << 16);
        o.y = (unsigned int)f_to_bf16(acc[2] * inv) | ((unsigned int)f_to_bf16(acc[3] * inv) << 16);
        o.z = (unsigned int)f_to_bf16(acc[4] * inv) | ((unsigned int)f_to_bf16(acc[5] * inv) << 16);
        o.w = (unsigned int)f_to_bf16(acc[6] * inv) | ((unsigned int)f_to_bf16(acc[7] * inv) << 16);
        reinterpret_cast<uint4*>(aggb)[(size_t)node * 16 + c] = o;
    }
}

// ---------------------------------------------------------------------------
// Layer 1 via MFMA 16x16x32 bf16. One wave per 16-node tile (3125 blocks).
// D: col = lane&15, row = (lane>>4)*4 + reg   [m89 verified mapping]
// ---------------------------------------------------------------------------
__global__ __launch_bounds__(64) void layer1_mfma_kernel(
    const unsigned short* __restrict__ aggb,
    const unsigned short* __restrict__ xb,
    const unsigned short* __restrict__ Wb,   // W1l@0, W1r@16384
    const float* __restrict__ b1,
    unsigned short* __restrict__ h1b)
{
    const int lane  = threadIdx.x;
    const int node0 = blockIdx.x * 16;
    const int c16   = lane & 15;
    const int kg    = lane >> 4;

    bf16x8 a[2][4];
    {
        const unsigned short* A0 = aggb + (size_t)(node0 + c16) * D + kg * 8;
        const unsigned short* A1 = xb   + (size_t)(node0 + c16) * D + kg * 8;
#pragma unroll
        for (int kf = 0; kf < 4; ++kf) {
            a[0][kf] = *reinterpret_cast<const bf16x8*>(A0 + kf * 32);
            a[1][kf] = *reinterpret_cast<const bf16x8*>(A1 + kf * 32);
        }
    }
    const unsigned short* WL = Wb;
    const unsigned short* WR = Wb + 16384;

#pragma unroll 2
    for (int jt = 0; jt < 8; ++jt) {
        f32x4 acc = {0.f, 0.f, 0.f, 0.f};
        const unsigned short* wl = WL + (size_t)(jt * 16 + c16) * D + kg * 8;
        const unsigned short* wr = WR + (size_t)(jt * 16 + c16) * D + kg * 8;
#pragma unroll
        for (int kf = 0; kf < 4; ++kf) {
            bf16x8 b = *reinterpret_cast<const bf16x8*>(wl + kf * 32);
            acc = __builtin_amdgcn_mfma_f32_16x16x32_bf16(a[0][kf], b, acc, 0, 0, 0);
        }
#pragma unroll
        for (int kf = 0; kf < 4; ++kf) {
            bf16x8 b = *reinterpret_cast<const bf16x8*>(wr + kf * 32);
            acc = __builtin_amdgcn_mfma_f32_16x16x32_bf16(a[1][kf], b, acc, 0, 0, 0);
        }
        const float bias = b1[jt * 16 + c16];
#pragma unroll
        for (int i = 0; i < 4; ++i) {
            float v = fmaxf(acc[i] + bias, 0.0f);
            h1b[(size_t)(node0 + kg * 4 + i) * D + jt * 16 + c16] = f_to_bf16(v);
        }
    }
}

// ---------------------------------------------------------------------------
// Layer 2 via MFMA + fused log_softmax over 64 outputs.
// ---------------------------------------------------------------------------
__global__ __launch_bounds__(64) void layer2_mfma_kernel(
    const unsigned short* __restrict__ aggb,
    const unsigned short* __restrict__ h1b,
    const unsigned short* __restrict__ Wb,   // W2l@32768, W2r@40960
    const float* __restrict__ b2,
    float* __restrict__ out)
{
    const int lane  = threadIdx.x;
    const int node0 = blockIdx.x * 16;
    const int c16   = lane & 15;
    const int kg    = lane >> 4;

    bf16x8 a[2][4];
    {
        const unsigned short* A0 = aggb + (size_t)(node0 + c16) * D + kg * 8;
        const unsigned short* A1 = h1b  + (size_t)(node0 + c16) * D + kg * 8;
#pragma unroll
        for (int kf = 0; kf < 4; ++kf) {
            a[0][kf] = *reinterpret_cast<const bf16x8*>(A0 + kf * 32);
            a[1][kf] = *reinterpret_cast<const bf16x8*>(A1 + kf * 32);
        }
    }
    const unsigned short* WL = Wb + 32768;
    const unsigned short* WR = Wb + 40960;

    f32x4 accs[4];
#pragma unroll
    for (int jt = 0; jt < 4; ++jt) {
        f32x4 acc = {0.f, 0.f, 0.f, 0.f};
        const unsigned short* wl = WL + (size_t)(jt * 16 + c16) * D + kg * 8;
        const unsigned short* wr = WR + (size_t)(jt * 16 + c16) * D + kg * 8;
#pragma unroll
        for (int kf = 0; kf < 4; ++kf) {
            bf16x8 b = *reinterpret_cast<const bf16x8*>(wl + kf * 32);
            acc = __builtin_amdgcn_mfma_f32_16x16x32_bf16(a[0][kf], b, acc, 0, 0, 0);
        }
#pragma unroll
        for (int kf = 0; kf < 4; ++kf) {
            bf16x8 b = *reinterpret_cast<const bf16x8*>(wr + kf * 32);
            acc = __builtin_amdgcn_mfma_f32_16x16x32_bf16(a[1][kf], b, acc, 0, 0, 0);
        }
        accs[jt] = acc;
    }

    float bias[4];
#pragma unroll
    for (int jt = 0; jt < 4; ++jt) bias[jt] = b2[jt * 16 + c16];

#pragma unroll
    for (int i = 0; i < 4; ++i) {
        float z[4];
        float m = -1e30f;
#pragma unroll
        for (int jt = 0; jt < 4; ++jt) {
            z[jt] = accs[jt][i] + bias[jt];
            m = fmaxf(m, z[jt]);
        }
#pragma unroll
        for (int off = 1; off < 16; off <<= 1)
            m = fmaxf(m, __shfl_xor(m, off));
        float s = 0.f;
#pragma unroll
        for (int jt = 0; jt < 4; ++jt) s += expf(z[jt] - m);
#pragma unroll
        for (int off = 1; off < 16; off <<= 1)
            s += __shfl_xor(s, off);
        float lse = m + logf(s);
        const int node = node0 + kg * 4 + i;
#pragma unroll
        for (int jt = 0; jt < 4; ++jt)
            out[(size_t)node * D_OUT + jt * 16 + c16] = z[jt] - lse;
    }
}

// ---------------------------------------------------------------------------
extern "C" void kernel_launch(void* const* d_in, const int* in_sizes, int n_in,
                              void* d_out, int out_size, void* d_ws, size_t ws_size,
                              hipStream_t stream)
{
    const float* x   = (const float*)d_in[0];
    const int*   ei  = (const int*)d_in[1];
    const float* W1l = (const float*)d_in[2];
    const float* b1  = (const float*)d_in[3];
    const float* W1r = (const float*)d_in[4];
    const float* W2l = (const float*)d_in[5];
    const float* b2  = (const float*)d_in[6];
    const float* W2r = (const float*)d_in[7];
    float* out = (float*)d_out;

    const int E = in_sizes[1] / 2;
    const int* src = ei;
    const int* dst = ei + E;

    // ---- workspace layout (256B-aligned chunks) ----
    char* base = (char*)d_ws;
    size_t off = 0;
    auto take = [&](size_t bytes) { char* p = base + off; off += (bytes + 255) & ~(size_t)255; return p; };

    unsigned short* xb   = (unsigned short*)take((size_t)N_NODES * D * 2);
    unsigned short* aggb = (unsigned short*)take((size_t)N_NODES * D * 2);
    unsigned short* h1b  = (unsigned short*)take((size_t)N_NODES * D * 2);
    unsigned short* Wb   = (unsigned short*)take((size_t)49152 * 2);
    int* degcur  = (int*)take((size_t)2 * N_NODES * 4);   // deg | cursor
    int* deg     = degcur;
    int* cursor  = degcur + N_NODES;
    int* row_ptr = (int*)take(((size_t)N_NODES + 1) * 4);
    int* part    = (int*)take((size_t)N_NODES * 4);
    int* bsum    = (int*)take((size_t)64 * 4);
    int* esrc    = (int*)take((size_t)E * 4);

    const int EB = (E + 255) / 256;
    const int SB = (N_NODES + 1023) / 1024;       // 49 scan blocks
    const int XB = (N_NODES * D / 8 + 255) / 256; // 3125 conv_x blocks

    zero_kernel<<<(2 * N_NODES / 4 + 255) / 256, 256, 0, stream>>>(degcur, 2 * N_NODES / 4);
    prep_kernel<<<XB + 24 + EB, 256, 0, stream>>>(x, xb, W1l, W1r, W2l, W2r, Wb, dst, deg, XB, E);
    scan1_kernel<<<SB, 256, 0, stream>>>(deg, part, bsum, N_NODES);
    scan2_kernel<<<1, 64, 0, stream>>>(bsum, row_ptr, SB, N_NODES);
    scan3_kernel<<<SB, 256, 0, stream>>>(part, bsum, row_ptr, N_NODES);
    fill_kernel<<<EB, 256, 0, stream>>>(src, dst, row_ptr, cursor, esrc, E);

    const int GB = (N_NODES + 3) / 4;            // gather: 4 nodes per block
    const int MB = N_NODES / 16;                 // 3125 MFMA tiles, exact

    // ---- layer 1 ----
    gather_bf16_kernel<<<GB, 256, 0, stream>>>(xb, row_ptr, esrc, aggb, N_NODES);
    layer1_mfma_kernel<<<MB, 64, 0, stream>>>(aggb, xb, Wb, b1, h1b);

    // ---- layer 2 ----
    gather_bf16_kernel<<<GB, 256, 0, stream>>>(h1b, row_ptr, esrc, aggb, N_NODES);
    layer2_mfma_kernel<<<MB, 64, 0, stream>>>(aggb, h1b, Wb, b2, out);
}

// Round 9
// 167.131 us; speedup vs baseline: 3.9617x; 1.0384x over previous
//
#include <hip/hip_runtime.h>
#include <math.h>

#define N_NODES 50000
#define D 128       // d_in == d_hid
#define D_OUT 64

typedef short bf16x8 __attribute__((ext_vector_type(8)));   // 8 bf16 (4 VGPR) MFMA frag
typedef float f32x4  __attribute__((ext_vector_type(4)));   // MFMA accumulator
typedef unsigned short u16x8 __attribute__((ext_vector_type(8)));

__device__ __forceinline__ unsigned short f_to_bf16(float f) {
    unsigned int u = __float_as_uint(f);
    u = (u + 0x7fffu + ((u >> 16) & 1u)) >> 16;   // RNE
    return (unsigned short)u;
}
__device__ __forceinline__ float bf16lo(unsigned int v) { return __uint_as_float(v << 16); }
__device__ __forceinline__ float bf16hi(unsigned int v) { return __uint_as_float(v & 0xffff0000u); }
__device__ __forceinline__ float bf16f(unsigned short v) { return __uint_as_float((unsigned int)v << 16); }

__device__ __forceinline__ void conv8(const float* __restrict__ src, unsigned short* __restrict__ dst, int i)
{
    float4 v0 = *reinterpret_cast<const float4*>(src + i);
    float4 v1 = *reinterpret_cast<const float4*>(src + i + 4);
    u16x8 o;
    o[0] = f_to_bf16(v0.x); o[1] = f_to_bf16(v0.y);
    o[2] = f_to_bf16(v0.z); o[3] = f_to_bf16(v0.w);
    o[4] = f_to_bf16(v1.x); o[5] = f_to_bf16(v1.y);
    o[6] = f_to_bf16(v1.z); o[7] = f_to_bf16(v1.w);
    *reinterpret_cast<u16x8*>(dst + i) = o;
}

__device__ __forceinline__ void acc_add(float* acc, uint4 v)
{
    acc[0] += bf16lo(v.x); acc[1] += bf16hi(v.x);
    acc[2] += bf16lo(v.y); acc[3] += bf16hi(v.y);
    acc[4] += bf16lo(v.z); acc[5] += bf16hi(v.z);
    acc[6] += bf16lo(v.w); acc[7] += bf16hi(v.w);
}

// ---------------------------------------------------------------------------
// Zero deg|cursor
// ---------------------------------------------------------------------------
__global__ __launch_bounds__(256) void zero_kernel(int* __restrict__ p, int n4)
{
    int i = blockIdx.x * 256 + threadIdx.x;
    if (i < n4) *reinterpret_cast<int4*>(p + i * 4) = make_int4(0, 0, 0, 0);
}

// ---------------------------------------------------------------------------
// Fused prep: conv_x | conv_w | hist, dispatched by block range.
// ---------------------------------------------------------------------------
__global__ __launch_bounds__(256) void prep_kernel(
    const float* __restrict__ x, unsigned short* __restrict__ xb,
    const float* __restrict__ w1l, const float* __restrict__ w1r,
    const float* __restrict__ w2l, const float* __restrict__ w2r,
    unsigned short* __restrict__ Wb,
    const int* __restrict__ dst, int* __restrict__ deg,
    int XB, int E)
{
    const int bx = blockIdx.x;
    if (bx < XB) {
        int i = (bx * 256 + threadIdx.x) * 8;
        if (i < N_NODES * D) conv8(x, xb, i);
    } else if (bx < XB + 24) {
        int i = ((bx - XB) * 256 + threadIdx.x) * 8;   // 49152 elems
        const float* src; int off;
        if      (i < 16384) { src = w1l; off = 0; }
        else if (i < 32768) { src = w1r; off = 16384; }
        else if (i < 40960) { src = w2l; off = 32768; }
        else                { src = w2r; off = 40960; }
        conv8(src, Wb + off, i - off);
    } else {
        int e = (bx - XB - 24) * 256 + threadIdx.x;
        if (e < E) atomicAdd(&deg[dst[e]], 1);
    }
}

// ---------------------------------------------------------------------------
// Hierarchical exclusive scan
// ---------------------------------------------------------------------------
__global__ __launch_bounds__(256) void scan1_kernel(
    const int* __restrict__ deg, int* __restrict__ part,
    int* __restrict__ bsum, int n)
{
    const int t = threadIdx.x;
    const int base = blockIdx.x * 1024 + t * 4;

    int a0 = 0, a1 = 0, a2 = 0, a3 = 0;
    if (base + 3 < n) {
        int4 v = *reinterpret_cast<const int4*>(deg + base);
        a0 = v.x; a1 = v.y; a2 = v.z; a3 = v.w;
    } else if (base < n) {
        a0 = deg[base];
        if (base + 1 < n) a1 = deg[base + 1];
        if (base + 2 < n) a2 = deg[base + 2];
    }
    const int s0 = a0, s1 = s0 + a1, s2 = s1 + a2, s3 = s2 + a3;

    const int lane = t & 63;
    int incl = s3;
#pragma unroll
    for (int off = 1; off < 64; off <<= 1) {
        int up = __shfl_up(incl, off);
        if (lane >= off) incl += up;
    }

    __shared__ int wsum[4];
    const int wid = t >> 6;
    if (lane == 63) wsum[wid] = incl;
    __syncthreads();

    int woff = 0;
#pragma unroll
    for (int w = 0; w < 4; ++w) woff += (w < wid) ? wsum[w] : 0;

    const int ex = woff + incl - s3;
    if (base + 3 < n) {
        int4 o; o.x = ex; o.y = ex + s0; o.z = ex + s1; o.w = ex + s2;
        *reinterpret_cast<int4*>(part + base) = o;
    } else if (base < n) {
        part[base] = ex;
        if (base + 1 < n) part[base + 1] = ex + s0;
        if (base + 2 < n) part[base + 2] = ex + s1;
    }
    if (t == 255) bsum[blockIdx.x] = woff + incl;
}

__global__ __launch_bounds__(64) void scan2_kernel(
    int* __restrict__ bsum, int* __restrict__ row_ptr, int nb, int n)
{
    const int t = threadIdx.x;
    int v = (t < nb) ? bsum[t] : 0;
    int incl = v;
#pragma unroll
    for (int off = 1; off < 64; off <<= 1) {
        int up = __shfl_up(incl, off);
        if (t >= off) incl += up;
    }
    if (t < nb) bsum[t] = incl - v;
    if (t == 63) row_ptr[n] = incl;
}

__global__ __launch_bounds__(256) void scan3_kernel(
    const int* __restrict__ part, const int* __restrict__ bsum,
    int* __restrict__ row_ptr, int n)
{
    const int base = blockIdx.x * 1024 + threadIdx.x * 4;
    const int add = bsum[blockIdx.x];
    if (base + 3 < n) {
        int4 v = *reinterpret_cast<const int4*>(part + base);
        v.x += add; v.y += add; v.z += add; v.w += add;
        *reinterpret_cast<int4*>(row_ptr + base) = v;
    } else if (base < n) {
        row_ptr[base] = part[base] + add;
        if (base + 1 < n) row_ptr[base + 1] = part[base + 1] + add;
        if (base + 2 < n) row_ptr[base + 2] = part[base + 2] + add;
    }
}

// ---------------------------------------------------------------------------
// CSR bucket-fill
// ---------------------------------------------------------------------------
__global__ __launch_bounds__(256) void fill_kernel(
    const int* __restrict__ src, const int* __restrict__ dst,
    const int* __restrict__ row_ptr, int* __restrict__ cursor,
    int* __restrict__ esrc, int E)
{
    int e = blockIdx.x * blockDim.x + threadIdx.x;
    if (e >= E) return;
    int d = dst[e];
    int pos = atomicAdd(&cursor[d], 1);
    esrc[row_ptr[d] + pos] = src[e];
}

// ---------------------------------------------------------------------------
// Gather-aggregate, templated on CHUNKS = uint4 chunks per row:
//   CHUNKS=16 -> 256B rows (width 128 bf16), 4 rows/load, 4 loads/iter
//   CHUNKS=8  -> 128B rows (width  64 bf16), 8 rows/load, 2 loads/iter
// 16 rows in flight per wave; lane-parallel esrc prefetch + shfl broadcast.
// ---------------------------------------------------------------------------
template<int CHUNKS>
__global__ __launch_bounds__(256) void gather_bf16_kernel(
    const unsigned short* __restrict__ xb,
    const int* __restrict__ row_ptr,
    const int* __restrict__ esrc,
    unsigned short* __restrict__ aggb,
    int n_nodes)
{
    constexpr int RPL = 64 / CHUNKS;        // rows per load instr
    constexpr int NLOADS = 16 / RPL;        // loads per iter (16 rows)
    const int wv   = threadIdx.x >> 6;
    const int lane = threadIdx.x & 63;
    const int node = blockIdx.x * 4 + wv;
    if (node >= n_nodes) return;

    const int beg = row_ptr[node];
    const int end = row_ptr[node + 1];
    const int g = lane / CHUNKS;            // row slot within load
    const int c = lane % CHUNKS;            // 16B column chunk

    const uint4* x4 = reinterpret_cast<const uint4*>(xb);

    float acc[8];
#pragma unroll
    for (int k = 0; k < 8; ++k) acc[k] = 0.f;

    for (int base = beg; base < end; base += 64) {
        const int cnt = min(end - base, 64);
        int s = (base + lane < end) ? esrc[base + lane] : 0;
        for (int i = 0; i < cnt; i += 16) {
            int pp[NLOADS];
            uint4 vv[NLOADS];
#pragma unroll
            for (int j = 0; j < NLOADS; ++j) {
                pp[j] = i + j * RPL + g;
                int sj = __shfl(s, pp[j]);
                vv[j] = x4[(size_t)sj * CHUNKS + c];
            }
#pragma unroll
            for (int j = 0; j < NLOADS; ++j)
                if (pp[j] < cnt) acc_add(acc, vv[j]);
        }
    }

    // combine row-slot groups (lanes sharing chunk c)
#pragma unroll
    for (int k = 0; k < 8; ++k) {
#pragma unroll
        for (int off = CHUNKS; off < 64; off <<= 1)
            acc[k] += __shfl_xor(acc[k], off);
    }

    if (g == 0) {
        const float inv = (end > beg) ? 1.0f / (float)(end - beg) : 0.0f;
        uint4 o;
        o.x = (unsigned int)f_to_bf16(acc[0] * inv) | ((unsigned int)f_to_bf16(acc[1] * inv) << 16);
        o.y = (unsigned int)f_to_bf16(acc[2] * inv) | ((unsigned int)f_to_bf16(acc[3] * inv) << 16);
        o.z = (unsigned int)f_to_bf16(acc[4] * inv) | ((unsigned int)f_to_bf16(acc[5] * inv) << 16);
        o.w = (unsigned int)f_to_bf16(acc[6] * inv) | ((unsigned int)f_to_bf16(acc[7] * inv) << 16);
        reinterpret_cast<uint4*>(aggb)[(size_t)node * CHUNKS + c] = o;
    }
}

// ---------------------------------------------------------------------------
// Layer 1 via MFMA 16x16x32 bf16, one wave per 16-node tile.
// Also emits t2 = h1 · W2l^T  ([N,64] bf16) via LDS-staged h1 tile, so the
// layer-2 aggregation gathers 128B rows (linearity: mean(h1)Wl = mean(h1 Wl)).
// D-layout: col = lane&15, row = (lane>>4)*4 + reg   [m89 verified]
// ---------------------------------------------------------------------------
__global__ __launch_bounds__(64) void layer1_mfma_kernel(
    const unsigned short* __restrict__ aggb,
    const unsigned short* __restrict__ xb,
    const unsigned short* __restrict__ Wb,   // W1l@0, W1r@16384, W2l@32768
    const float* __restrict__ b1,
    unsigned short* __restrict__ h1b,
    unsigned short* __restrict__ t2b)        // [N,64]
{
    __shared__ unsigned short h1s[16][144];  // padded: 288B rows, 16B-aligned

    const int lane  = threadIdx.x;
    const int node0 = blockIdx.x * 16;
    const int c16   = lane & 15;
    const int kg    = lane >> 4;

    bf16x8 a[2][4];
    {
        const unsigned short* A0 = aggb + (size_t)(node0 + c16) * D + kg * 8;
        const unsigned short* A1 = xb   + (size_t)(node0 + c16) * D + kg * 8;
#pragma unroll
        for (int kf = 0; kf < 4; ++kf) {
            a[0][kf] = *reinterpret_cast<const bf16x8*>(A0 + kf * 32);
            a[1][kf] = *reinterpret_cast<const bf16x8*>(A1 + kf * 32);
        }
    }
    const unsigned short* WL = Wb;
    const unsigned short* WR = Wb + 16384;

#pragma unroll 2
    for (int jt = 0; jt < 8; ++jt) {
        f32x4 acc = {0.f, 0.f, 0.f, 0.f};
        const unsigned short* wl = WL + (size_t)(jt * 16 + c16) * D + kg * 8;
        const unsigned short* wr = WR + (size_t)(jt * 16 + c16) * D + kg * 8;
#pragma unroll
        for (int kf = 0; kf < 4; ++kf) {
            bf16x8 b = *reinterpret_cast<const bf16x8*>(wl + kf * 32);
            acc = __builtin_amdgcn_mfma_f32_16x16x32_bf16(a[0][kf], b, acc, 0, 0, 0);
        }
#pragma unroll
        for (int kf = 0; kf < 4; ++kf) {
            bf16x8 b = *reinterpret_cast<const bf16x8*>(wr + kf * 32);
            acc = __builtin_amdgcn_mfma_f32_16x16x32_bf16(a[1][kf], b, acc, 0, 0, 0);
        }
        const float bias = b1[jt * 16 + c16];
#pragma unroll
        for (int i = 0; i < 4; ++i) {
            float v = fmaxf(acc[i] + bias, 0.0f);
            unsigned short us = f_to_bf16(v);
            h1b[(size_t)(node0 + kg * 4 + i) * D + jt * 16 + c16] = us;
            h1s[kg * 4 + i][jt * 16 + c16] = us;
        }
    }

    __syncthreads();

    // t2 = h1_tile (16x128) · W2l^T (64x128)^T -> 16x64
    bf16x8 a2[4];
#pragma unroll
    for (int kf = 0; kf < 4; ++kf)
        a2[kf] = *reinterpret_cast<const bf16x8*>(&h1s[c16][kg * 8 + kf * 32]);

    const unsigned short* W2L = Wb + 32768;
#pragma unroll
    for (int jt = 0; jt < 4; ++jt) {
        f32x4 acc = {0.f, 0.f, 0.f, 0.f};
        const unsigned short* wl = W2L + (size_t)(jt * 16 + c16) * D + kg * 8;
#pragma unroll
        for (int kf = 0; kf < 4; ++kf) {
            bf16x8 b = *reinterpret_cast<const bf16x8*>(wl + kf * 32);
            acc = __builtin_amdgcn_mfma_f32_16x16x32_bf16(a2[kf], b, acc, 0, 0, 0);
        }
#pragma unroll
        for (int i = 0; i < 4; ++i)
            t2b[(size_t)(node0 + kg * 4 + i) * D_OUT + jt * 16 + c16] = f_to_bf16(acc[i]);
    }
}

// ---------------------------------------------------------------------------
// Layer 2: out = log_softmax( agg(t2) + b2 + h1·W2r^T ).
// Left term arrives premeaned in agg2b [N,64]; only the right GEMM remains.
// ---------------------------------------------------------------------------
__global__ __launch_bounds__(64) void layer2_mfma_kernel(
    const unsigned short* __restrict__ agg2b,   // [N,64] premeaned t2
    const unsigned short* __restrict__ h1b,
    const unsigned short* __restrict__ Wb,      // W2r@40960
    const float* __restrict__ b2,
    float* __restrict__ out)
{
    const int lane  = threadIdx.x;
    const int node0 = blockIdx.x * 16;
    const int c16   = lane & 15;
    const int kg    = lane >> 4;

    bf16x8 a[4];
    {
        const unsigned short* A1 = h1b + (size_t)(node0 + c16) * D + kg * 8;
#pragma unroll
        for (int kf = 0; kf < 4; ++kf)
            a[kf] = *reinterpret_cast<const bf16x8*>(A1 + kf * 32);
    }
    const unsigned short* WR = Wb + 40960;

    f32x4 accs[4];
#pragma unroll
    for (int jt = 0; jt < 4; ++jt) {
        f32x4 acc = {0.f, 0.f, 0.f, 0.f};
        const unsigned short* wr = WR + (size_t)(jt * 16 + c16) * D + kg * 8;
#pragma unroll
        for (int kf = 0; kf < 4; ++kf) {
            bf16x8 b = *reinterpret_cast<const bf16x8*>(wr + kf * 32);
            acc = __builtin_amdgcn_mfma_f32_16x16x32_bf16(a[kf], b, acc, 0, 0, 0);
        }
        accs[jt] = acc;
    }

    float bias[4];
#pragma unroll
    for (int jt = 0; jt < 4; ++jt) bias[jt] = b2[jt * 16 + c16];

#pragma unroll
    for (int i = 0; i < 4; ++i) {
        const int node = node0 + kg * 4 + i;
        float z[4];
        float m = -1e30f;
#pragma unroll
        for (int jt = 0; jt < 4; ++jt) {
            float lft = bf16f(agg2b[(size_t)node * D_OUT + jt * 16 + c16]);
            z[jt] = lft + accs[jt][i] + bias[jt];
            m = fmaxf(m, z[jt]);
        }
#pragma unroll
        for (int off = 1; off < 16; off <<= 1)
            m = fmaxf(m, __shfl_xor(m, off));
        float s = 0.f;
#pragma unroll
        for (int jt = 0; jt < 4; ++jt) s += expf(z[jt] - m);
#pragma unroll
        for (int off = 1; off < 16; off <<= 1)
            s += __shfl_xor(s, off);
        float lse = m + logf(s);
#pragma unroll
        for (int jt = 0; jt < 4; ++jt)
            out[(size_t)node * D_OUT + jt * 16 + c16] = z[jt] - lse;
    }
}

// ---------------------------------------------------------------------------
extern "C" void kernel_launch(void* const* d_in, const int* in_sizes, int n_in,
                              void* d_out, int out_size, void* d_ws, size_t ws_size,
                              hipStream_t stream)
{
    const float* x   = (const float*)d_in[0];
    const int*   ei  = (const int*)d_in[1];
    const float* W1l = (const float*)d_in[2];
    const float* b1  = (const float*)d_in[3];
    const float* W1r = (const float*)d_in[4];
    const float* W2l = (const float*)d_in[5];
    const float* b2  = (const float*)d_in[6];
    const float* W2r = (const float*)d_in[7];
    float* out = (float*)d_out;

    const int E = in_sizes[1] / 2;
    const int* src = ei;
    const int* dst = ei + E;

    // ---- workspace layout (256B-aligned chunks) ----
    char* base = (char*)d_ws;
    size_t off = 0;
    auto take = [&](size_t bytes) { char* p = base + off; off += (bytes + 255) & ~(size_t)255; return p; };

    unsigned short* xb    = (unsigned short*)take((size_t)N_NODES * D * 2);
    unsigned short* aggb  = (unsigned short*)take((size_t)N_NODES * D * 2);
    unsigned short* h1b   = (unsigned short*)take((size_t)N_NODES * D * 2);
    unsigned short* t2b   = (unsigned short*)take((size_t)N_NODES * D_OUT * 2);
    unsigned short* agg2b = (unsigned short*)take((size_t)N_NODES * D_OUT * 2);
    unsigned short* Wb    = (unsigned short*)take((size_t)49152 * 2);
    int* degcur  = (int*)take((size_t)2 * N_NODES * 4);   // deg | cursor
    int* deg     = degcur;
    int* cursor  = degcur + N_NODES;
    int* row_ptr = (int*)take(((size_t)N_NODES + 1) * 4);
    int* part    = (int*)take((size_t)N_NODES * 4);
    int* bsum    = (int*)take((size_t)64 * 4);
    int* esrc    = (int*)take((size_t)E * 4);

    const int EB = (E + 255) / 256;
    const int SB = (N_NODES + 1023) / 1024;       // 49 scan blocks
    const int XB = (N_NODES * D / 8 + 255) / 256; // 3125 conv_x blocks

    zero_kernel<<<(2 * N_NODES / 4 + 255) / 256, 256, 0, stream>>>(degcur, 2 * N_NODES / 4);
    prep_kernel<<<XB + 24 + EB, 256, 0, stream>>>(x, xb, W1l, W1r, W2l, W2r, Wb, dst, deg, XB, E);
    scan1_kernel<<<SB, 256, 0, stream>>>(deg, part, bsum, N_NODES);
    scan2_kernel<<<1, 64, 0, stream>>>(bsum, row_ptr, SB, N_NODES);
    scan3_kernel<<<SB, 256, 0, stream>>>(part, bsum, row_ptr, N_NODES);
    fill_kernel<<<EB, 256, 0, stream>>>(src, dst, row_ptr, cursor, esrc, E);

    const int GB = (N_NODES + 3) / 4;            // gather: 4 nodes per block
    const int MB = N_NODES / 16;                 // 3125 MFMA tiles, exact

    // ---- layer 1 (+ t2 = h1·W2l^T) ----
    gather_bf16_kernel<16><<<GB, 256, 0, stream>>>(xb, row_ptr, esrc, aggb, N_NODES);
    layer1_mfma_kernel<<<MB, 64, 0, stream>>>(aggb, xb, Wb, b1, h1b, t2b);

    // ---- layer 2 (gather over 128B t2 rows) ----
    gather_bf16_kernel<8><<<GB, 256, 0, stream>>>(t2b, row_ptr, esrc, agg2b, N_NODES);
    layer2_mfma_kernel<<<MB, 64, 0, stream>>>(agg2b, h1b, Wb, b2, out);
}